// Round 4
// baseline (1772.937 us; speedup 1.0000x reference)
//
#include <hip/hip_runtime.h>

#define BN 200
#define VN 64
#define HIDD 64
#define FINN 32
#define NSW 10
#define EC 63
#define MNE 73

typedef unsigned short u16;
typedef unsigned int u32;

__device__ __forceinline__ float bfu(u16 u) { return __uint_as_float(((u32)u) << 16); }
__device__ __forceinline__ u16 f2bf(float f) {
    u32 x = __float_as_uint(f);
    u32 r = x + 0x7fffu + ((x >> 16) & 1u);
    return (u16)(r >> 16);
}

// full-wave (64-lane) LayerNorm helper: returns relu((e-mean)*rsqrt(var+eps))
__device__ __forceinline__ float ln_relu64(float e) {
    float s1 = e, s2 = e * e;
#pragma unroll
    for (int m = 1; m < 64; m <<= 1) {
        s1 += __shfl_xor(s1, m);
        s2 += __shfl_xor(s2, m);
    }
    float mean = s1 * 0.015625f;
    float var = fmaxf(s2 * 0.015625f - mean * mean, 0.f);
    return fmaxf((e - mean) * rsqrtf(var + 1e-5f), 0.f);
}

// -------- dtype detector: A[0,1]==1.0 -> bf16 iff u16[1]==0x3F80 (fp32: u16[1]=hi half of A[0]=0) --------
__global__ void k_detect(const u16* __restrict__ A_u16, int* __restrict__ flag) {
    if (threadIdx.x == 0) *flag = (A_u16[1] == 0x3F80) ? 1 : 0;
}

struct CvtArgs {
    const void* src[21];
    int cnt[21];
};

__global__ __launch_bounds__(256) void k_convert(CvtArgs args, float* __restrict__ dst,
                                                 const int* __restrict__ flag, int total) {
    int fl = *flag;
    for (int idx = blockIdx.x * 256 + threadIdx.x; idx < total; idx += gridDim.x * 256) {
        int seg = 0, off = idx;
        while (off >= args.cnt[seg]) { off -= args.cnt[seg]; ++seg; }
        float v;
        if (fl) v = bfu(((const u16*)args.src[seg])[off]);
        else    v = ((const float*)args.src[seg])[off];
        dst[idx] = v;
    }
}

// -------- setup: conn = min(A+S,1), deg_inv, ews = embed_s @ p0_Ws (2x64) --------
__global__ void k_setup(const float* __restrict__ A, const float* __restrict__ S,
                        const float* __restrict__ emb, const float* __restrict__ p0Ws,
                        float* __restrict__ conn, float* __restrict__ dinv,
                        float* __restrict__ ews) {
    int t = threadIdx.x;
    for (int i = t; i < VN * VN; i += 256)
        conn[i] = fminf(A[i] + S[i], 1.0f);
    if (t < 128) {
        int j = t >> 6, k = t & 63;
        float a = 0.f;
        for (int h = 0; h < FINN; h++) a += emb[j * FINN + h] * p0Ws[h * HIDD + k];
        ews[(j << 6) + k] = a;
    }
    __syncthreads();
    if (t < VN) {
        float d = 0.f;
        for (int q = 0; q < VN; q++) d += conn[t * VN + q];
        dinv[t] = 1.0f / fmaxf(d, 1.0f);
    }
}

// -------- node transforms: xi=x@Wi, xj=x@Wj, xv=x@Vw, xu=x@U --------
__global__ __launch_bounds__(256) void k_xw(const float* __restrict__ x, int Hin,
                                            const float* __restrict__ Wi, const float* __restrict__ Wj,
                                            const float* __restrict__ Vw, const float* __restrict__ U,
                                            float* __restrict__ xi, float* __restrict__ xj,
                                            float* __restrict__ xv, float* __restrict__ xu) {
    __shared__ float xr[64];
    int row = blockIdx.x, t = threadIdx.x;
    if (t < Hin) xr[t] = x[(size_t)row * Hin + t];
    __syncthreads();
    int which = t >> 6, k = t & 63;
    const float* W = (which == 0) ? Wi : (which == 1) ? Wj : (which == 2) ? Vw : U;
    float* out = (which == 0) ? xi : (which == 1) ? xj : (which == 2) ? xv : xu;
    float a = 0.f;
    for (int h = 0; h < Hin; h++) a += xr[h] * W[h * HIDD + k];
    out[(size_t)row * HIDD + k] = a;
}

// -------- msg for layer 0: s1 = relu(LN(ews[S] + xi0 + xj0)); gate; mean-agg --------
__global__ __launch_bounds__(256) void k_msg0(const float* __restrict__ ews, const float* __restrict__ S,
                                              const float* __restrict__ conn, const float* __restrict__ dinv,
                                              const float* __restrict__ xi0, const float* __restrict__ xj0,
                                              const float* __restrict__ xv, float* __restrict__ msg) {
    __shared__ float mp[4][64];
    int t = threadIdx.x, blk = blockIdx.x;
    int b = blk >> 6, v = blk & 63, lane = t & 63, wid = t >> 6;
    float xiv = xi0[((size_t)blk << 6) + lane];
    float acc = 0.f;
    for (int q = 0; q < 16; q++) {
        int w = (wid << 4) + q;
        int sidx = (S[(v << 6) + w] != 0.f) ? 1 : 0;
        float e = ews[(sidx << 6) + lane] + xiv + xj0[((((size_t)b << 6) + w) << 6) + lane];
        float s1 = ln_relu64(e);
        float g = conn[(v << 6) + w] / (1.f + __expf(-s1));
        acc += g * xv[((((size_t)b << 6) + w) << 6) + lane];
    }
    mp[wid][lane] = acc;
    __syncthreads();
    if (t < 64)
        msg[((size_t)blk << 6) + t] = (mp[0][t] + mp[1][t] + mp[2][t] + mp[3][t]) * dinv[v];
}

// -------- msg for layer 1: recompute s1, then s2 = s1 + relu(LN(s1@Ws1 + xi1 + xj1)) --------
__global__ __launch_bounds__(256) void k_msg1(const float* __restrict__ ews, const float* __restrict__ S,
                                              const float* __restrict__ conn, const float* __restrict__ dinv,
                                              const float* __restrict__ xi0, const float* __restrict__ xj0,
                                              const float* __restrict__ xi1, const float* __restrict__ xj1,
                                              const float* __restrict__ Ws1, const float* __restrict__ xv,
                                              float* __restrict__ msg) {
    __shared__ float sT[64][64];
    __shared__ float wsL[64][64];
    __shared__ float mp[4][64];
    int t = threadIdx.x, blk = blockIdx.x;
    int b = blk >> 6, v = blk & 63, lane = t & 63, wid = t >> 6;

    float xiv0 = xi0[((size_t)blk << 6) + lane];
    for (int q = 0; q < 16; q++) {
        int w = (wid << 4) + q;
        int sidx = (S[(v << 6) + w] != 0.f) ? 1 : 0;
        float e = ews[(sidx << 6) + lane] + xiv0 + xj0[((((size_t)b << 6) + w) << 6) + lane];
        sT[w][lane] = ln_relu64(e);
    }
    for (int i = t; i < 4096; i += 256) ((float*)wsL)[i] = Ws1[i];
    __syncthreads();

    float xiv1 = xi1[((size_t)blk << 6) + lane];
    float acc = 0.f;
    for (int q = 0; q < 16; q++) {
        int w = (wid << 4) + q;
        float a = 0.f;
#pragma unroll 8
        for (int h = 0; h < 64; h++) a += sT[w][h] * wsL[h][lane];
        float e = a + xiv1 + xj1[((((size_t)b << 6) + w) << 6) + lane];
        float s2v = sT[w][lane] + ln_relu64(e);
        float g = conn[(v << 6) + w] / (1.f + __expf(-s2v));
        acc += g * xv[((((size_t)b << 6) + w) << 6) + lane];
    }
    mp[wid][lane] = acc;
    __syncthreads();
    if (t < 64)
        msg[((size_t)blk << 6) + t] = (mp[0][t] + mp[1][t] + mp[2][t] + mp[3][t]) * dinv[v];
}

// -------- msg for layer 2: chain s1 -> s2 -> s3; gate with xv2 --------
__global__ __launch_bounds__(256) void k_msg2(const float* __restrict__ ews, const float* __restrict__ S,
                                              const float* __restrict__ conn, const float* __restrict__ dinv,
                                              const float* __restrict__ xi0, const float* __restrict__ xj0,
                                              const float* __restrict__ xi1, const float* __restrict__ xj1,
                                              const float* __restrict__ xi2, const float* __restrict__ xj2,
                                              const float* __restrict__ Ws1, const float* __restrict__ Ws2,
                                              const float* __restrict__ xv, float* __restrict__ msg) {
    __shared__ float sT[64][64];
    __shared__ float wsL[64][64];
    __shared__ float mp[4][64];
    int t = threadIdx.x, blk = blockIdx.x;
    int b = blk >> 6, v = blk & 63, lane = t & 63, wid = t >> 6;

    // stage 1: s1 -> sT, Ws1 -> wsL
    float xiv0 = xi0[((size_t)blk << 6) + lane];
    for (int q = 0; q < 16; q++) {
        int w = (wid << 4) + q;
        int sidx = (S[(v << 6) + w] != 0.f) ? 1 : 0;
        float e = ews[(sidx << 6) + lane] + xiv0 + xj0[((((size_t)b << 6) + w) << 6) + lane];
        sT[w][lane] = ln_relu64(e);
    }
    for (int i = t; i < 4096; i += 256) ((float*)wsL)[i] = Ws1[i];
    __syncthreads();

    // stage 2: s2 into registers
    float xiv1 = xi1[((size_t)blk << 6) + lane];
    float s2r[16];
    for (int q = 0; q < 16; q++) {
        int w = (wid << 4) + q;
        float a = 0.f;
#pragma unroll 8
        for (int h = 0; h < 64; h++) a += sT[w][h] * wsL[h][lane];
        float e = a + xiv1 + xj1[((((size_t)b << 6) + w) << 6) + lane];
        s2r[q] = sT[w][lane] + ln_relu64(e);
    }
    __syncthreads();   // all stage-2 reads of sT/wsL complete

    // write back s2, load Ws2
    for (int q = 0; q < 16; q++) sT[(wid << 4) + q][lane] = s2r[q];
    for (int i = t; i < 4096; i += 256) ((float*)wsL)[i] = Ws2[i];
    __syncthreads();

    // stage 3: s3 + gate + aggregate
    float xiv2 = xi2[((size_t)blk << 6) + lane];
    float acc = 0.f;
    for (int q = 0; q < 16; q++) {
        int w = (wid << 4) + q;
        float a = 0.f;
#pragma unroll 8
        for (int h = 0; h < 64; h++) a += sT[w][h] * wsL[h][lane];
        float e = a + xiv2 + xj2[((((size_t)b << 6) + w) << 6) + lane];
        float s3v = sT[w][lane] + ln_relu64(e);
        float g = conn[(v << 6) + w] / (1.f + __expf(-s3v));
        acc += g * xv[((((size_t)b << 6) + w) << 6) + lane];
    }
    mp[wid][lane] = acc;
    __syncthreads();
    if (t < 64)
        msg[((size_t)blk << 6) + t] = (mp[0][t] + mp[1][t] + mp[2][t] + mp[3][t]) * dinv[v];
}

// -------- node update: x = (first ? h : x + h), h = relu(LN(xu + msg)) --------
__global__ __launch_bounds__(256) void k_node(const float* __restrict__ xu, const float* __restrict__ msg,
                                              float* __restrict__ x_cur, int first) {
    int t = threadIdx.x;
    size_t row = (size_t)blockIdx.x * 4 + (t >> 6);
    int lane = t & 63;
    size_t idx = (row << 6) + lane;
    float z = xu[idx] + msg[idx];
    float h = ln_relu64(z);
    x_cur[idx] = first ? h : x_cur[idx] + h;
}

// -------- x_g = sum over v --------
__global__ void k_xg(const float* __restrict__ x_cur, float* __restrict__ xg) {
    int b = blockIdx.x, k = threadIdx.x;
    float a = 0.f;
    for (int vv = 0; vv < VN; vv++) a += x_cur[((size_t)b * VN + vv) * HIDD + k];
    xg[b * HIDD + k] = a;
}

// -------- switch head: recompute s3[si,sj] chain, then MLP 256->256->4 --------
__global__ __launch_bounds__(256) void k_smlp(const float* __restrict__ ews, const float* __restrict__ S,
                                              const float* __restrict__ Ws1, const float* __restrict__ Ws2,
                                              const float* __restrict__ xi0, const float* __restrict__ xj0,
                                              const float* __restrict__ xi1, const float* __restrict__ xj1,
                                              const float* __restrict__ xi2, const float* __restrict__ xj2,
                                              const float* __restrict__ x3, const float* __restrict__ xg,
                                              const int* __restrict__ eS,
                                              const float* __restrict__ W1, const float* __restrict__ W2,
                                              float* __restrict__ out) {
    __shared__ float sv[64];
    __shared__ float in_lds[256];
    __shared__ float hid[256];
    int blk = blockIdx.x;
    int b = blk / NSW, e = blk % NSW;
    int si = eS[e], sj = eS[NSW + e];
    int t = threadIdx.x, lane = t & 63, wid = t >> 6;
    size_t ri = ((size_t)b << 6) + si, rj = ((size_t)b << 6) + sj;

    if (wid == 0) {
        int sidx = (S[(si << 6) + sj] != 0.f) ? 1 : 0;
        float e1 = ews[(sidx << 6) + lane] + xi0[(ri << 6) + lane] + xj0[(rj << 6) + lane];
        sv[lane] = ln_relu64(e1);
    }
    __syncthreads();
    float s2v = 0.f;
    if (wid == 0) {
        float a = 0.f;
        for (int h = 0; h < 64; h++) a += sv[h] * Ws1[(h << 6) + lane];
        float e2 = a + xi1[(ri << 6) + lane] + xj1[(rj << 6) + lane];
        s2v = sv[lane] + ln_relu64(e2);
    }
    __syncthreads();
    if (wid == 0) sv[lane] = s2v;
    __syncthreads();
    if (wid == 0) {
        float a = 0.f;
        for (int h = 0; h < 64; h++) a += sv[h] * Ws2[(h << 6) + lane];
        float e3 = a + xi2[(ri << 6) + lane] + xj2[(rj << 6) + lane];
        in_lds[lane] = sv[lane] + ln_relu64(e3);
    } else if (wid == 1) {
        in_lds[t] = x3[(ri << 6) + lane];
    } else if (wid == 2) {
        in_lds[t] = x3[(rj << 6) + lane];
    } else {
        in_lds[t] = xg[(b << 6) + lane];
    }
    __syncthreads();
    float a = 0.f;
    for (int i = 0; i < 256; i++) a += in_lds[i] * W1[i * 256 + t];
    hid[t] = fmaxf(a, 0.f);
    __syncthreads();
    if (t < 4) {
        float o = 0.f;
        for (int i = 0; i < 256; i++) o += hid[i] * W2[i * 4 + t];
        out[((size_t)b * NSW + e) * 4 + t] = 1.f / (1.f + __expf(-o));
    }
}

// -------- connection head: MLP 192->192->3 --------
__global__ __launch_bounds__(192) void k_cmlp(const float* __restrict__ x_cur, const float* __restrict__ xg,
                                              const int* __restrict__ eA,
                                              const float* __restrict__ W1, const float* __restrict__ W2,
                                              float* __restrict__ out) {
    __shared__ float in_lds[192];
    __shared__ float hid[192];
    int blk = blockIdx.x;
    int b = blk / EC, e = blk % EC;
    int ai = eA[e], aj = eA[EC + e];
    int t = threadIdx.x;
    int seg = t >> 6, j = t & 63;
    float val = (seg == 0) ? x_cur[(((size_t)b << 6) + ai) * 64 + j]
              : (seg == 1) ? x_cur[(((size_t)b << 6) + aj) * 64 + j]
                           : xg[(b << 6) + j];
    in_lds[t] = val;
    __syncthreads();
    float a = 0.f;
    for (int i = 0; i < 192; i++) a += in_lds[i] * W1[i * 192 + t];
    hid[t] = fmaxf(a, 0.f);
    __syncthreads();
    if (t < 3) {
        float o = 0.f;
        for (int i = 0; i < 192; i++) o += hid[i] * W2[i * 3 + t];
        out[((size_t)b * EC + e) * 3 + t] = 1.f / (1.f + __expf(-o));
    }
}

// -------- final assembly: [p_flow(73), v(64), graph_topo(73)]; store dtype per flag --------
__global__ __launch_bounds__(256) void k_final(const float* __restrict__ sm, const float* __restrict__ cm,
                                               const float* __restrict__ Dinv, const float* __restrict__ Incp,
                                               const float* __restrict__ Incc, const int* __restrict__ flag,
                                               void* __restrict__ out_v) {
    int b = blockIdx.x, t = threadIdx.x;
    if (t >= 2 * MNE + VN) return;
    float val;
    if (t < MNE) {
        val = (t < EC) ? cm[((size_t)b * EC + t) * 3 + 0] - 0.5f
                       : sm[((size_t)b * NSW + (t - EC)) * 4 + 1] - 0.5f;
    } else if (t < MNE + VN) {
        int i = t - MNE;
        if (i == 0) {
            val = 1.0f;
        } else {
            float acc = 0.f;
            for (int m = 0; m < MNE; m++) {
                float ip = Incp[i * MNE + m];
                float ic = Incc[i * MNE + m];
                if (ip != 0.f || ic != 0.f) {
                    float vp, vc;
                    if (m < EC) {
                        const float* c = cm + ((size_t)b * EC + m) * 3;
                        vp = 0.9f + 0.2f * c[1];
                        vc = 0.9f + 0.2f * c[2];
                    } else {
                        const float* s = sm + ((size_t)b * NSW + (m - EC)) * 4;
                        vp = 0.9f + 0.2f * s[2];
                        vc = 0.9f + 0.2f * s[3];
                    }
                    acc += ip * vp + ic * vc;
                }
            }
            val = acc * Dinv[i * VN + i];
        }
    } else {
        int m = t - (MNE + VN);
        val = (m < EC) ? 1.0f : sm[((size_t)b * NSW + (m - EC)) * 4 + 0];
    }
    size_t oidx = (size_t)b * (2 * MNE + VN) + t;
    if (*flag) ((u16*)out_v)[oidx] = f2bf(val);     // bf16-variant problems
    else       ((float*)out_v)[oidx] = val;         // fp32 (reference declares float32)
}

extern "C" void kernel_launch(void* const* d_in, const int* in_sizes, int n_in,
                              void* d_out, int out_size, void* d_ws, size_t ws_size,
                              hipStream_t stream) {
    const int* eA = (const int*)d_in[21];
    const int* eS = (const int*)d_in[22];

    float* pool = (float*)d_ws;

    int off[22];
    off[0] = 0;
    for (int i = 0; i < 21; i++) off[i + 1] = off[i] + in_sizes[i];
    int cvt_total = off[21];

    const float* P_x    = pool + off[0];
    const float* P_A    = pool + off[1];
    const float* P_S    = pool + off[2];
    const float* P_emb  = pool + off[3];
    const float* P_p0Ws = pool + off[4];
    const float* P_p0Wi = pool + off[5];
    const float* P_p0Wj = pool + off[6];
    const float* P_p0U  = pool + off[7];
    const float* P_p0V  = pool + off[8];
    const float* P_plWs = pool + off[9];
    const float* P_plWi = pool + off[10];
    const float* P_plWj = pool + off[11];
    const float* P_plU  = pool + off[12];
    const float* P_plV  = pool + off[13];
    const float* P_smW1 = pool + off[14];
    const float* P_smW2 = pool + off[15];
    const float* P_cmW1 = pool + off[16];
    const float* P_cmW2 = pool + off[17];
    const float* P_Dinv = pool + off[18];
    const float* P_Incp = pool + off[19];
    const float* P_Incc = pool + off[20];

    const int NR = BN * VN * HIDD;           // 819,200
    float* tail = pool + cvt_total;
    float* xi0 = tail;            float* xi1 = xi0 + NR;  float* xi2 = xi1 + NR;
    float* xj0 = xi2 + NR;        float* xj1 = xj0 + NR;  float* xj2 = xj1 + NR;
    float* xv  = xj2 + NR;        float* xu  = xv + NR;
    float* x_cur = xu + NR;       float* msg = x_cur + NR;
    float* xg   = msg + NR;                  // 12800
    float* conn = xg + 12800;                // 4096
    float* dinv = conn + 4096;               // 64
    float* ews  = dinv + 64;                 // 128
    float* smo  = ews + 128;                 // 8000
    float* cmo  = smo + 8000;                // 37800
    int*   flag = (int*)(cmo + 37800);

    k_detect<<<1, 64, 0, stream>>>((const u16*)d_in[1], flag);

    CvtArgs ca;
    for (int i = 0; i < 21; i++) { ca.src[i] = d_in[i]; ca.cnt[i] = in_sizes[i]; }
    k_convert<<<(cvt_total + 255) / 256, 256, 0, stream>>>(ca, pool, flag, cvt_total);

    k_setup<<<1, 256, 0, stream>>>(P_A, P_S, P_emb, P_p0Ws, conn, dinv, ews);

    // layer 0 (first): Hin=32
    k_xw<<<BN * VN, 256, 0, stream>>>(P_x, FINN, P_p0Wi, P_p0Wj, P_p0V, P_p0U, xi0, xj0, xv, xu);
    k_msg0<<<BN * VN, 256, 0, stream>>>(ews, P_S, conn, dinv, xi0, xj0, xv, msg);
    k_node<<<BN * VN / 4, 256, 0, stream>>>(xu, msg, x_cur, 1);

    // layer 1
    k_xw<<<BN * VN, 256, 0, stream>>>(x_cur, HIDD, P_plWi, P_plWj, P_plV, P_plU, xi1, xj1, xv, xu);
    k_msg1<<<BN * VN, 256, 0, stream>>>(ews, P_S, conn, dinv, xi0, xj0, xi1, xj1, P_plWs, xv, msg);
    k_node<<<BN * VN / 4, 256, 0, stream>>>(xu, msg, x_cur, 0);

    // layer 2
    k_xw<<<BN * VN, 256, 0, stream>>>(x_cur, HIDD, P_plWi + 4096, P_plWj + 4096,
                                      P_plV + 4096, P_plU + 4096, xi2, xj2, xv, xu);
    k_msg2<<<BN * VN, 256, 0, stream>>>(ews, P_S, conn, dinv, xi0, xj0, xi1, xj1, xi2, xj2,
                                        P_plWs, P_plWs + 4096, xv, msg);
    k_node<<<BN * VN / 4, 256, 0, stream>>>(xu, msg, x_cur, 0);

    k_xg<<<BN, 64, 0, stream>>>(x_cur, xg);
    k_smlp<<<BN * NSW, 256, 0, stream>>>(ews, P_S, P_plWs, P_plWs + 4096,
                                         xi0, xj0, xi1, xj1, xi2, xj2,
                                         x_cur, xg, eS, P_smW1, P_smW2, smo);
    k_cmlp<<<BN * EC, 192, 0, stream>>>(x_cur, xg, eA, P_cmW1, P_cmW2, cmo);
    k_final<<<BN, 256, 0, stream>>>(smo, cmo, P_Dinv, P_Incp, P_Incc, flag, d_out);
}

// Round 5
// 583.164 us; speedup vs baseline: 3.0402x; 3.0402x over previous
//
#include <hip/hip_runtime.h>

#define BN 200
#define VN 64
#define HIDD 64
#define FINN 32
#define NSW 10
#define EC 63
#define MNE 73

typedef unsigned short u16;
typedef unsigned int u32;
typedef __attribute__((ext_vector_type(8))) short bf16x8;
typedef __attribute__((ext_vector_type(4))) float f32x4;

__device__ __forceinline__ float bfu(u16 u) { return __uint_as_float(((u32)u) << 16); }
__device__ __forceinline__ u16 f2bf(float f) {
    u32 x = __float_as_uint(f);
    u32 r = x + 0x7fffu + ((x >> 16) & 1u);
    return (u16)(r >> 16);
}

// full-wave (64-lane) LayerNorm helper (used by head/node kernels)
__device__ __forceinline__ float ln_relu64(float e) {
    float s1 = e, s2 = e * e;
#pragma unroll
    for (int m = 1; m < 64; m <<= 1) {
        s1 += __shfl_xor(s1, m);
        s2 += __shfl_xor(s2, m);
    }
    float mean = s1 * 0.015625f;
    float var = fmaxf(s2 * 0.015625f - mean * mean, 0.f);
    return fmaxf((e - mean) * rsqrtf(var + 1e-5f), 0.f);
}

// -------- dtype detector: A[0,1]==1.0 -> bf16 iff u16[1]==0x3F80 --------
__global__ void k_detect(const u16* __restrict__ A_u16, int* __restrict__ flag) {
    if (threadIdx.x == 0) *flag = (A_u16[1] == 0x3F80) ? 1 : 0;
}

struct CvtArgs {
    const void* src[21];
    int cnt[21];
};

__global__ __launch_bounds__(256) void k_convert(CvtArgs args, float* __restrict__ dst,
                                                 const int* __restrict__ flag, int total) {
    int fl = *flag;
    for (int idx = blockIdx.x * 256 + threadIdx.x; idx < total; idx += gridDim.x * 256) {
        int seg = 0, off = idx;
        while (off >= args.cnt[seg]) { off -= args.cnt[seg]; ++seg; }
        float v;
        if (fl) v = bfu(((const u16*)args.src[seg])[off]);
        else    v = ((const float*)args.src[seg])[off];
        dst[idx] = v;
    }
}

// -------- setup: conn, deg_inv, ews = embed_s@p0_Ws, and Bp = frag-packed bf16 Ws1/Ws2 --------
// Bp layout per layer: [nt][kb][lane][j] (nt stride 1024, kb 512, lane 8), element =
// bf16(Ws[kb*32 + (lane>>4)*8 + j][nt*16 + (lane&15)])  — B-operand frag order for 16x16x32.
__global__ void k_setup(const float* __restrict__ A, const float* __restrict__ S,
                        const float* __restrict__ emb, const float* __restrict__ p0Ws,
                        const float* __restrict__ plWs,
                        float* __restrict__ conn, float* __restrict__ dinv,
                        float* __restrict__ ews, u16* __restrict__ Bp) {
    int t = threadIdx.x;
    for (int i = t; i < VN * VN; i += 256)
        conn[i] = fminf(A[i] + S[i], 1.0f);
    for (int l = 0; l < 2; l++) {
        const float* Ws = plWs + l * 4096;
        for (int i = t; i < 4096; i += 256) {
            int nt = i >> 10, kb = (i >> 9) & 1, ln = (i >> 3) & 63, j = i & 7;
            int k_ = kb * 32 + (ln >> 4) * 8 + j;
            int n_ = nt * 16 + (ln & 15);
            Bp[l * 4096 + i] = f2bf(Ws[k_ * 64 + n_]);
        }
    }
    if (t < 128) {
        int j = t >> 6, k = t & 63;
        float a = 0.f;
        for (int h = 0; h < FINN; h++) a += emb[j * FINN + h] * p0Ws[h * HIDD + k];
        ews[(j << 6) + k] = a;
    }
    __syncthreads();
    if (t < VN) {
        float d = 0.f;
        for (int q = 0; q < VN; q++) d += conn[t * VN + q];
        dinv[t] = 1.0f / fmaxf(d, 1.0f);
    }
}

// -------- node transforms: xi=x@Wi, xj=x@Wj, xv=x@Vw, xu=x@U --------
__global__ __launch_bounds__(256) void k_xw(const float* __restrict__ x, int Hin,
                                            const float* __restrict__ Wi, const float* __restrict__ Wj,
                                            const float* __restrict__ Vw, const float* __restrict__ U,
                                            float* __restrict__ xi, float* __restrict__ xj,
                                            float* __restrict__ xv, float* __restrict__ xu) {
    __shared__ float xr[64];
    int row = blockIdx.x, t = threadIdx.x;
    if (t < Hin) xr[t] = x[(size_t)row * Hin + t];
    __syncthreads();
    int which = t >> 6, k = t & 63;
    const float* W = (which == 0) ? Wi : (which == 1) ? Wj : (which == 2) ? Vw : U;
    float* out = (which == 0) ? xi : (which == 1) ? xj : (which == 2) ? xv : xu;
    float a = 0.f;
    for (int h = 0; h < Hin; h++) a += xr[h] * W[h * HIDD + k];
    out[(size_t)row * HIDD + k] = a;
}

// -------- unified msg kernel: s-chain with nmat MFMA stages, then gate+mean-agg --------
// block = (b,v), 4 waves. Wave wid owns w-rows [16wid,16wid+16).
// Per-lane: q=lane>>4, c=lane&15. C-layout state s[r][nt] = s[w=16wid+4q+r][k=nt*16+c].
__global__ __launch_bounds__(256) void k_msgM(
    const float* __restrict__ ews, const float* __restrict__ S,
    const float* __restrict__ conn, const float* __restrict__ dinv,
    const float* __restrict__ xi0, const float* __restrict__ xj0,
    const float* __restrict__ xi1, const float* __restrict__ xj1,
    const float* __restrict__ xi2, const float* __restrict__ xj2,
    const u16* __restrict__ Bp, const float* __restrict__ xv,
    float* __restrict__ msg, int nmat)
{
    __shared__ u16 sA[64][72];       // bf16 A-operand staging, padded stride 72
    __shared__ float xiL[3][64];
    __shared__ float sS[64];
    __shared__ float connL[64];
    __shared__ float ewsL[128];
    __shared__ float mp[4][64];

    int t = threadIdx.x, blk = blockIdx.x;
    int b = blk >> 6, v = blk & 63;
    int lane = t & 63, wid = t >> 6, q = lane >> 4, c = lane & 15;

    if (t < 64) {
        xiL[0][t] = xi0[((size_t)blk << 6) + t];
        xiL[1][t] = xi1[((size_t)blk << 6) + t];
        xiL[2][t] = xi2[((size_t)blk << 6) + t];
        sS[t] = S[(v << 6) + t];
        connL[t] = conn[(v << 6) + t];
    } else if (t < 192) {
        ewsL[t - 64] = ews[t - 64];
    }
    __syncthreads();

    const int wbase = (wid << 4) + (q << 2);
    const size_t rowb = (size_t)b << 6;

    float s[4][4];

    // ---- stage 0: s1 = relu(LN(ews[S] + xi0 + xj0)) ----
#pragma unroll
    for (int r = 0; r < 4; r++) {
        int w_ = wbase + r;
        int si = (sS[w_] != 0.f) ? 64 : 0;
        const float* xjrow = xj0 + ((rowb + w_) << 6);
#pragma unroll
        for (int nt = 0; nt < 4; nt++) {
            int k_ = (nt << 4) + c;
            s[r][nt] = ewsL[si + k_] + xiL[0][k_] + xjrow[k_];
        }
    }
#pragma unroll
    for (int r = 0; r < 4; r++) {
        float s1 = s[r][0] + s[r][1] + s[r][2] + s[r][3];
        float s2 = s[r][0]*s[r][0] + s[r][1]*s[r][1] + s[r][2]*s[r][2] + s[r][3]*s[r][3];
#pragma unroll
        for (int m = 1; m < 16; m <<= 1) { s1 += __shfl_xor(s1, m); s2 += __shfl_xor(s2, m); }
        float mean = s1 * 0.015625f;
        float var = fmaxf(s2 * 0.015625f - mean * mean, 0.f);
        float rinv = rsqrtf(var + 1e-5f);
        int w_ = wbase + r;
#pragma unroll
        for (int nt = 0; nt < 4; nt++) {
            float h = fmaxf((s[r][nt] - mean) * rinv, 0.f);
            s[r][nt] = h;
            if (nmat > 0) sA[w_][(nt << 4) + c] = f2bf(h);
        }
    }

    // ---- matmul stages: e = s@Ws + xi + xj; s += relu(LN(e)) ----
    for (int ms = 0; ms < nmat; ms++) {
        const float* xjN = (ms == 0) ? xj1 : xj2;
        const u16* BpL = Bp + ms * 4096;
        // A-frags from this wave's own slab rows (lane reads row 16wid+c)
        bf16x8 a0 = *(const bf16x8*)&sA[(wid << 4) + c][(q << 3)];
        bf16x8 a1 = *(const bf16x8*)&sA[(wid << 4) + c][32 + (q << 3)];
        float enew[4][4];
#pragma unroll
        for (int nt = 0; nt < 4; nt++) {
            const u16* bp = BpL + (nt << 10) + (lane << 3);
            bf16x8 b0 = *(const bf16x8*)(bp);
            bf16x8 b1 = *(const bf16x8*)(bp + 512);
            f32x4 acc = {0.f, 0.f, 0.f, 0.f};
            acc = __builtin_amdgcn_mfma_f32_16x16x32_bf16(a0, b0, acc, 0, 0, 0);
            acc = __builtin_amdgcn_mfma_f32_16x16x32_bf16(a1, b1, acc, 0, 0, 0);
#pragma unroll
            for (int r = 0; r < 4; r++) enew[r][nt] = acc[r];
        }
#pragma unroll
        for (int r = 0; r < 4; r++) {
            int w_ = wbase + r;
            const float* xjrow = xjN + ((rowb + w_) << 6);
#pragma unroll
            for (int nt = 0; nt < 4; nt++)
                enew[r][nt] += xiL[ms + 1][(nt << 4) + c] + xjrow[(nt << 4) + c];
            float s1 = enew[r][0] + enew[r][1] + enew[r][2] + enew[r][3];
            float s2 = enew[r][0]*enew[r][0] + enew[r][1]*enew[r][1]
                     + enew[r][2]*enew[r][2] + enew[r][3]*enew[r][3];
#pragma unroll
            for (int m = 1; m < 16; m <<= 1) { s1 += __shfl_xor(s1, m); s2 += __shfl_xor(s2, m); }
            float mean = s1 * 0.015625f;
            float var = fmaxf(s2 * 0.015625f - mean * mean, 0.f);
            float rinv = rsqrtf(var + 1e-5f);
#pragma unroll
            for (int nt = 0; nt < 4; nt++) {
                float h = fmaxf((enew[r][nt] - mean) * rinv, 0.f);
                s[r][nt] += h;
            }
            if (ms + 1 < nmat) {
#pragma unroll
                for (int nt = 0; nt < 4; nt++) sA[w_][(nt << 4) + c] = f2bf(s[r][nt]);
            }
        }
    }

    // ---- gate + mean aggregation ----
    float acck[4] = {0.f, 0.f, 0.f, 0.f};
#pragma unroll
    for (int r = 0; r < 4; r++) {
        int w_ = wbase + r;
        const float* xvrow = xv + ((rowb + w_) << 6);
        float cw = connL[w_];
#pragma unroll
        for (int nt = 0; nt < 4; nt++) {
            float g = cw / (1.f + __expf(-s[r][nt]));
            acck[nt] += g * xvrow[(nt << 4) + c];
        }
    }
#pragma unroll
    for (int nt = 0; nt < 4; nt++) {
        acck[nt] += __shfl_xor(acck[nt], 16);
        acck[nt] += __shfl_xor(acck[nt], 32);
    }
    if (q == 0) {
#pragma unroll
        for (int nt = 0; nt < 4; nt++) mp[wid][(nt << 4) + c] = acck[nt];
    }
    __syncthreads();
    if (t < 64)
        msg[((size_t)blk << 6) + t] = (mp[0][t] + mp[1][t] + mp[2][t] + mp[3][t]) * dinv[v];
}

// -------- node update --------
__global__ __launch_bounds__(256) void k_node(const float* __restrict__ xu, const float* __restrict__ msg,
                                              float* __restrict__ x_cur, int first) {
    int t = threadIdx.x;
    size_t row = (size_t)blockIdx.x * 4 + (t >> 6);
    int lane = t & 63;
    size_t idx = (row << 6) + lane;
    float z = xu[idx] + msg[idx];
    float h = ln_relu64(z);
    x_cur[idx] = first ? h : x_cur[idx] + h;
}

// -------- x_g = sum over v --------
__global__ void k_xg(const float* __restrict__ x_cur, float* __restrict__ xg) {
    int b = blockIdx.x, k = threadIdx.x;
    float a = 0.f;
    for (int vv = 0; vv < VN; vv++) a += x_cur[((size_t)b * VN + vv) * HIDD + k];
    xg[b * HIDD + k] = a;
}

// -------- switch head: recompute s3[si,sj] chain in fp32, then MLP 256->256->4 --------
__global__ __launch_bounds__(256) void k_smlp(const float* __restrict__ ews, const float* __restrict__ S,
                                              const float* __restrict__ Ws1, const float* __restrict__ Ws2,
                                              const float* __restrict__ xi0, const float* __restrict__ xj0,
                                              const float* __restrict__ xi1, const float* __restrict__ xj1,
                                              const float* __restrict__ xi2, const float* __restrict__ xj2,
                                              const float* __restrict__ x3, const float* __restrict__ xg,
                                              const int* __restrict__ eS,
                                              const float* __restrict__ W1, const float* __restrict__ W2,
                                              float* __restrict__ out) {
    __shared__ float sv[64];
    __shared__ float in_lds[256];
    __shared__ float hid[256];
    int blk = blockIdx.x;
    int b = blk / NSW, e = blk % NSW;
    int si = eS[e], sj = eS[NSW + e];
    int t = threadIdx.x, lane = t & 63, wid = t >> 6;
    size_t ri = ((size_t)b << 6) + si, rj = ((size_t)b << 6) + sj;

    if (wid == 0) {
        int sidx = (S[(si << 6) + sj] != 0.f) ? 1 : 0;
        float e1 = ews[(sidx << 6) + lane] + xi0[(ri << 6) + lane] + xj0[(rj << 6) + lane];
        sv[lane] = ln_relu64(e1);
    }
    __syncthreads();
    float s2v = 0.f;
    if (wid == 0) {
        float a = 0.f;
        for (int h = 0; h < 64; h++) a += sv[h] * Ws1[(h << 6) + lane];
        float e2 = a + xi1[(ri << 6) + lane] + xj1[(rj << 6) + lane];
        s2v = sv[lane] + ln_relu64(e2);
    }
    __syncthreads();
    if (wid == 0) sv[lane] = s2v;
    __syncthreads();
    if (wid == 0) {
        float a = 0.f;
        for (int h = 0; h < 64; h++) a += sv[h] * Ws2[(h << 6) + lane];
        float e3 = a + xi2[(ri << 6) + lane] + xj2[(rj << 6) + lane];
        in_lds[lane] = sv[lane] + ln_relu64(e3);
    } else if (wid == 1) {
        in_lds[t] = x3[(ri << 6) + lane];
    } else if (wid == 2) {
        in_lds[t] = x3[(rj << 6) + lane];
    } else {
        in_lds[t] = xg[(b << 6) + lane];
    }
    __syncthreads();
    float a = 0.f;
    for (int i = 0; i < 256; i++) a += in_lds[i] * W1[i * 256 + t];
    hid[t] = fmaxf(a, 0.f);
    __syncthreads();
    if (t < 4) {
        float o = 0.f;
        for (int i = 0; i < 256; i++) o += hid[i] * W2[i * 4 + t];
        out[((size_t)b * NSW + e) * 4 + t] = 1.f / (1.f + __expf(-o));
    }
}

// -------- connection head: MLP 192->192->3 --------
__global__ __launch_bounds__(192) void k_cmlp(const float* __restrict__ x_cur, const float* __restrict__ xg,
                                              const int* __restrict__ eA,
                                              const float* __restrict__ W1, const float* __restrict__ W2,
                                              float* __restrict__ out) {
    __shared__ float in_lds[192];
    __shared__ float hid[192];
    int blk = blockIdx.x;
    int b = blk / EC, e = blk % EC;
    int ai = eA[e], aj = eA[EC + e];
    int t = threadIdx.x;
    int seg = t >> 6, j = t & 63;
    float val = (seg == 0) ? x_cur[(((size_t)b << 6) + ai) * 64 + j]
              : (seg == 1) ? x_cur[(((size_t)b << 6) + aj) * 64 + j]
                           : xg[(b << 6) + j];
    in_lds[t] = val;
    __syncthreads();
    float a = 0.f;
    for (int i = 0; i < 192; i++) a += in_lds[i] * W1[i * 192 + t];
    hid[t] = fmaxf(a, 0.f);
    __syncthreads();
    if (t < 3) {
        float o = 0.f;
        for (int i = 0; i < 192; i++) o += hid[i] * W2[i * 3 + t];
        out[((size_t)b * EC + e) * 3 + t] = 1.f / (1.f + __expf(-o));
    }
}

// -------- final assembly --------
__global__ __launch_bounds__(256) void k_final(const float* __restrict__ sm, const float* __restrict__ cm,
                                               const float* __restrict__ Dinv, const float* __restrict__ Incp,
                                               const float* __restrict__ Incc, const int* __restrict__ flag,
                                               void* __restrict__ out_v) {
    int b = blockIdx.x, t = threadIdx.x;
    if (t >= 2 * MNE + VN) return;
    float val;
    if (t < MNE) {
        val = (t < EC) ? cm[((size_t)b * EC + t) * 3 + 0] - 0.5f
                       : sm[((size_t)b * NSW + (t - EC)) * 4 + 1] - 0.5f;
    } else if (t < MNE + VN) {
        int i = t - MNE;
        if (i == 0) {
            val = 1.0f;
        } else {
            float acc = 0.f;
            for (int m = 0; m < MNE; m++) {
                float ip = Incp[i * MNE + m];
                float ic = Incc[i * MNE + m];
                if (ip != 0.f || ic != 0.f) {
                    float vp, vc;
                    if (m < EC) {
                        const float* cc = cm + ((size_t)b * EC + m) * 3;
                        vp = 0.9f + 0.2f * cc[1];
                        vc = 0.9f + 0.2f * cc[2];
                    } else {
                        const float* ss = sm + ((size_t)b * NSW + (m - EC)) * 4;
                        vp = 0.9f + 0.2f * ss[2];
                        vc = 0.9f + 0.2f * ss[3];
                    }
                    acc += ip * vp + ic * vc;
                }
            }
            val = acc * Dinv[i * VN + i];
        }
    } else {
        int m = t - (MNE + VN);
        val = (m < EC) ? 1.0f : sm[((size_t)b * NSW + (m - EC)) * 4 + 0];
    }
    size_t oidx = (size_t)b * (2 * MNE + VN) + t;
    if (*flag) ((u16*)out_v)[oidx] = f2bf(val);
    else       ((float*)out_v)[oidx] = val;
}

extern "C" void kernel_launch(void* const* d_in, const int* in_sizes, int n_in,
                              void* d_out, int out_size, void* d_ws, size_t ws_size,
                              hipStream_t stream) {
    const int* eA = (const int*)d_in[21];
    const int* eS = (const int*)d_in[22];

    float* pool = (float*)d_ws;

    int off[22];
    off[0] = 0;
    for (int i = 0; i < 21; i++) off[i + 1] = off[i] + in_sizes[i];
    int cvt_total = off[21];

    const float* P_x    = pool + off[0];
    const float* P_A    = pool + off[1];
    const float* P_S    = pool + off[2];
    const float* P_emb  = pool + off[3];
    const float* P_p0Ws = pool + off[4];
    const float* P_p0Wi = pool + off[5];
    const float* P_p0Wj = pool + off[6];
    const float* P_p0U  = pool + off[7];
    const float* P_p0V  = pool + off[8];
    const float* P_plWs = pool + off[9];
    const float* P_plWi = pool + off[10];
    const float* P_plWj = pool + off[11];
    const float* P_plU  = pool + off[12];
    const float* P_plV  = pool + off[13];
    const float* P_smW1 = pool + off[14];
    const float* P_smW2 = pool + off[15];
    const float* P_cmW1 = pool + off[16];
    const float* P_cmW2 = pool + off[17];
    const float* P_Dinv = pool + off[18];
    const float* P_Incp = pool + off[19];
    const float* P_Incc = pool + off[20];

    const int NR = BN * VN * HIDD;           // 819,200
    float* tail = pool + ((cvt_total + 7) & ~7);
    float* xi0 = tail;            float* xi1 = xi0 + NR;  float* xi2 = xi1 + NR;
    float* xj0 = xi2 + NR;        float* xj1 = xj0 + NR;  float* xj2 = xj1 + NR;
    float* xv  = xj2 + NR;        float* xu  = xv + NR;
    float* x_cur = xu + NR;       float* msg = x_cur + NR;
    float* xg   = msg + NR;                  // 12800
    float* conn = xg + 12800;                // 4096
    float* dinv = conn + 4096;               // 64
    float* ews  = dinv + 64;                 // 128
    float* smo  = ews + 128;                 // 8000
    float* cmo  = smo + 8000;                // 37800
    u16*   Bp   = (u16*)(cmo + 37800);       // 8192 u16 = 16 KB (16B-aligned: float8 boundary)
    int*   flag = (int*)(Bp + 8192);

    k_detect<<<1, 64, 0, stream>>>((const u16*)d_in[1], flag);

    CvtArgs ca;
    for (int i = 0; i < 21; i++) { ca.src[i] = d_in[i]; ca.cnt[i] = in_sizes[i]; }
    k_convert<<<(cvt_total + 255) / 256, 256, 0, stream>>>(ca, pool, flag, cvt_total);

    k_setup<<<1, 256, 0, stream>>>(P_A, P_S, P_emb, P_p0Ws, P_plWs, conn, dinv, ews, Bp);

    // layer 0 (first): Hin=32, no matmul stage
    k_xw<<<BN * VN, 256, 0, stream>>>(P_x, FINN, P_p0Wi, P_p0Wj, P_p0V, P_p0U, xi0, xj0, xv, xu);
    k_msgM<<<BN * VN, 256, 0, stream>>>(ews, P_S, conn, dinv, xi0, xj0, xi0, xj0, xi0, xj0,
                                        Bp, xv, msg, 0);
    k_node<<<BN * VN / 4, 256, 0, stream>>>(xu, msg, x_cur, 1);

    // layer 1: one matmul stage (Ws1)
    k_xw<<<BN * VN, 256, 0, stream>>>(x_cur, HIDD, P_plWi, P_plWj, P_plV, P_plU, xi1, xj1, xv, xu);
    k_msgM<<<BN * VN, 256, 0, stream>>>(ews, P_S, conn, dinv, xi0, xj0, xi1, xj1, xi1, xj1,
                                        Bp, xv, msg, 1);
    k_node<<<BN * VN / 4, 256, 0, stream>>>(xu, msg, x_cur, 0);

    // layer 2: two matmul stages (Ws1, Ws2)
    k_xw<<<BN * VN, 256, 0, stream>>>(x_cur, HIDD, P_plWi + 4096, P_plWj + 4096,
                                      P_plV + 4096, P_plU + 4096, xi2, xj2, xv, xu);
    k_msgM<<<BN * VN, 256, 0, stream>>>(ews, P_S, conn, dinv, xi0, xj0, xi1, xj1, xi2, xj2,
                                        Bp, xv, msg, 2);
    k_node<<<BN * VN / 4, 256, 0, stream>>>(xu, msg, x_cur, 0);

    k_xg<<<BN, 64, 0, stream>>>(x_cur, xg);
    k_smlp<<<BN * NSW, 256, 0, stream>>>(ews, P_S, P_plWs, P_plWs + 4096,
                                         xi0, xj0, xi1, xj1, xi2, xj2,
                                         x_cur, xg, eS, P_smW1, P_smW2, smo);
    k_cmlp<<<BN * EC, 192, 0, stream>>>(x_cur, xg, eA, P_cmW1, P_cmW2, cmo);
    k_final<<<BN, 256, 0, stream>>>(smo, cmo, P_Dinv, P_Incp, P_Incc, flag, d_out);
}

// Round 6
// 420.888 us; speedup vs baseline: 4.2124x; 1.3856x over previous
//
#include <hip/hip_runtime.h>

#define BN 200
#define VN 64
#define HIDD 64
#define FINN 32
#define NSW 10
#define EC 63
#define MNE 73
#define NE_MAX 256

typedef unsigned short u16;
typedef unsigned int u32;

__device__ __forceinline__ float bfu(u16 u) { return __uint_as_float(((u32)u) << 16); }
__device__ __forceinline__ u16 f2bf(float f) {
    u32 x = __float_as_uint(f);
    u32 r = x + 0x7fffu + ((x >> 16) & 1u);
    return (u16)(r >> 16);
}

// full-wave (64-lane) LayerNorm helper: relu((e-mean)*rsqrt(var+eps))
__device__ __forceinline__ float ln_relu64(float e) {
    float s1 = e, s2 = e * e;
#pragma unroll
    for (int m = 1; m < 64; m <<= 1) {
        s1 += __shfl_xor(s1, m);
        s2 += __shfl_xor(s2, m);
    }
    float mean = s1 * 0.015625f;
    float var = fmaxf(s2 * 0.015625f - mean * mean, 0.f);
    return fmaxf((e - mean) * rsqrtf(var + 1e-5f), 0.f);
}

// -------- dtype detector --------
__global__ void k_detect(const u16* __restrict__ A_u16, int* __restrict__ flag) {
    if (threadIdx.x == 0) *flag = (A_u16[1] == 0x3F80) ? 1 : 0;
}

struct CvtArgs {
    const void* src[21];
    int cnt[21];
};

__global__ __launch_bounds__(256) void k_convert(CvtArgs args, float* __restrict__ dst,
                                                 const int* __restrict__ flag, int total) {
    int fl = *flag;
    for (int idx = blockIdx.x * 256 + threadIdx.x; idx < total; idx += gridDim.x * 256) {
        int seg = 0, off = idx;
        while (off >= args.cnt[seg]) { off -= args.cnt[seg]; ++seg; }
        float v;
        if (fl) v = bfu(((const u16*)args.src[seg])[off]);
        else    v = ((const float*)args.src[seg])[off];
        dst[idx] = v;
    }
}

// -------- setup: conn, deg_inv, ews, CSR edge list (v-major), switch->edge map --------
__global__ void k_setup(const float* __restrict__ A, const float* __restrict__ S,
                        const float* __restrict__ emb, const float* __restrict__ p0Ws,
                        const int* __restrict__ eS,
                        float* __restrict__ conn, float* __restrict__ dinv,
                        float* __restrict__ ews,
                        int* __restrict__ row_ptr, int* __restrict__ colp,
                        int* __restrict__ sw_eidx) {
    __shared__ int degL[64];
    __shared__ int rpL[65];
    int t = threadIdx.x;
    for (int i = t; i < VN * VN; i += 256)
        conn[i] = fminf(A[i] + S[i], 1.0f);
    if (t < 128) {
        int j = t >> 6, k = t & 63;
        float a = 0.f;
        for (int h = 0; h < FINN; h++) a += emb[j * FINN + h] * p0Ws[h * HIDD + k];
        ews[(j << 6) + k] = a;
    }
    __syncthreads();
    if (t < 64) {
        int d = 0;
        for (int w = 0; w < 64; w++) if (conn[t * 64 + w] != 0.f) d++;
        degL[t] = d;
        dinv[t] = 1.0f / fmaxf((float)d, 1.0f);
    }
    __syncthreads();
    if (t == 0) {
        int cum = 0;
        for (int v = 0; v < 64; v++) { rpL[v] = cum; cum += degL[v]; }
        rpL[64] = cum;
        for (int v = 0; v <= 64; v++) row_ptr[v] = rpL[v];
    }
    __syncthreads();
    if (t < 64) {
        int pos = rpL[t];
        for (int w = 0; w < 64; w++)
            if (conn[t * 64 + w] != 0.f)
                colp[pos++] = w | ((S[t * 64 + w] != 0.f) ? 256 : 0);
    }
    __syncthreads();
    if (t < NSW) {
        int si = eS[t], sj = eS[NSW + t];
        int idx = 0;
        for (int e = rpL[si]; e < rpL[si + 1]; e++)
            if ((colp[e] & 255) == sj) idx = e;
        sw_eidx[t] = idx;
    }
}

// -------- node transforms: xi=x@Wi, xj=x@Wj, xv=x@Vw, xu=x@U --------
__global__ __launch_bounds__(256) void k_xw(const float* __restrict__ x, int Hin,
                                            const float* __restrict__ Wi, const float* __restrict__ Wj,
                                            const float* __restrict__ Vw, const float* __restrict__ U,
                                            float* __restrict__ xi, float* __restrict__ xj,
                                            float* __restrict__ xv, float* __restrict__ xu) {
    __shared__ float xr[64];
    int row = blockIdx.x, t = threadIdx.x;
    if (t < Hin) xr[t] = x[(size_t)row * Hin + t];
    __syncthreads();
    int which = t >> 6, k = t & 63;
    const float* W = (which == 0) ? Wi : (which == 1) ? Wj : (which == 2) ? Vw : U;
    float* out = (which == 0) ? xi : (which == 1) ? xj : (which == 2) ? xv : xu;
    float a = 0.f;
    for (int h = 0; h < Hin; h += 4) {
        float4 x4 = *(const float4*)&xr[h];
        a += x4.x * W[(h + 0) * HIDD + k] + x4.y * W[(h + 1) * HIDD + k]
           + x4.z * W[(h + 2) * HIDD + k] + x4.w * W[(h + 3) * HIDD + k];
    }
    out[(size_t)row * HIDD + k] = a;
}

// -------- sparse edge kernel: per (b,v) wave, chain s at CSR edges, gate+mean-agg --------
// layer 0: s = relu(LN(ews[S] + xi + xj))
// layer>=1: s += relu(LN(s@Ws + xi + xj))   (s persisted in s_edge)
__global__ __launch_bounds__(256) void k_edge(
    const float* __restrict__ ews, const float* __restrict__ Ws,
    const int* __restrict__ row_ptr, const int* __restrict__ colp,
    const float* __restrict__ dinv,
    const float* __restrict__ xi, const float* __restrict__ xj,
    const float* __restrict__ xv,
    float* __restrict__ s_edge, float* __restrict__ msg, int layer)
{
    int t = threadIdx.x, blk = blockIdx.x;
    int b = blk >> 4, vg = blk & 15;
    int wid = t >> 6, lane = t & 63;
    int v = (vg << 2) + wid;
    size_t rowb = (size_t)b << 6;

    // preload Ws column `lane` into registers (layers >= 1)
    float wreg[64];
    if (layer > 0) {
#pragma unroll
        for (int h = 0; h < 64; h++) wreg[h] = Ws[h * 64 + lane];
    }

    int e0 = __builtin_amdgcn_readfirstlane(row_ptr[v]);
    int e1 = __builtin_amdgcn_readfirstlane(row_ptr[v + 1]);
    float xival = xi[((rowb + v) << 6) + lane];
    float acc = 0.f;

    for (int e = e0; e < e1; e++) {
        int cp = __builtin_amdgcn_readfirstlane(colp[e]);
        int w = cp & 255;
        float xjv = xj[((rowb + w) << 6) + lane];
        float* srow = s_edge + (((size_t)b * NE_MAX + e) << 6);
        float sout;
        if (layer == 0) {
            int sidx = (cp >> 8) & 1;
            float ee = ews[(sidx << 6) + lane] + xival + xjv;
            sout = ln_relu64(ee);
        } else {
            float sp = srow[lane];
            float a = 0.f;
#pragma unroll
            for (int h = 0; h < 64; h++) a += srow[h] * wreg[h];   // srow[h]: wave-uniform scalar loads
            float ee = a + xival + xjv;
            sout = sp + ln_relu64(ee);
        }
        srow[lane] = sout;
        acc += xv[((rowb + w) << 6) + lane] / (1.f + __expf(-sout));
    }
    msg[((rowb + v) << 6) + lane] = acc * dinv[v];
}

// -------- node update --------
__global__ __launch_bounds__(256) void k_node(const float* __restrict__ xu, const float* __restrict__ msg,
                                              float* __restrict__ x_cur, int first) {
    int t = threadIdx.x;
    size_t row = (size_t)blockIdx.x * 4 + (t >> 6);
    int lane = t & 63;
    size_t idx = (row << 6) + lane;
    float z = xu[idx] + msg[idx];
    float h = ln_relu64(z);
    x_cur[idx] = first ? h : x_cur[idx] + h;
}

// -------- x_g = sum over v --------
__global__ void k_xg(const float* __restrict__ x_cur, float* __restrict__ xg) {
    int b = blockIdx.x, k = threadIdx.x;
    float a = 0.f;
    for (int vv = 0; vv < VN; vv++) a += x_cur[((size_t)b * VN + vv) * HIDD + k];
    xg[b * HIDD + k] = a;
}

// -------- switch head: gather s3 from s_edge, MLP 256->256->4 --------
__global__ __launch_bounds__(256) void k_smlp(const float* __restrict__ s_edge,
                                              const int* __restrict__ sw_eidx,
                                              const int* __restrict__ eS,
                                              const float* __restrict__ x3, const float* __restrict__ xg,
                                              const float* __restrict__ W1, const float* __restrict__ W2,
                                              float* __restrict__ out) {
    __shared__ float in_lds[256];
    __shared__ float hid[256];
    int blk = blockIdx.x;
    int b = blk / NSW, e = blk % NSW;
    int si = eS[e], sj = eS[NSW + e];
    int t = threadIdx.x, lane = t & 63, wid = t >> 6;
    float val;
    if (wid == 0)      val = s_edge[(((size_t)b * NE_MAX + sw_eidx[e]) << 6) + lane];
    else if (wid == 1) val = x3[(((size_t)b << 6) + si) * 64 + lane];
    else if (wid == 2) val = x3[(((size_t)b << 6) + sj) * 64 + lane];
    else               val = xg[(b << 6) + lane];
    in_lds[t] = val;
    __syncthreads();
    float a = 0.f;
    for (int i = 0; i < 256; i++) a += in_lds[i] * W1[i * 256 + t];
    hid[t] = fmaxf(a, 0.f);
    __syncthreads();
    if (t < 4) {
        float o = 0.f;
        for (int i = 0; i < 256; i++) o += hid[i] * W2[i * 4 + t];
        out[((size_t)b * NSW + e) * 4 + t] = 1.f / (1.f + __expf(-o));
    }
}

// -------- connection head: MLP 192->192->3 --------
__global__ __launch_bounds__(192) void k_cmlp(const float* __restrict__ x_cur, const float* __restrict__ xg,
                                              const int* __restrict__ eA,
                                              const float* __restrict__ W1, const float* __restrict__ W2,
                                              float* __restrict__ out) {
    __shared__ float in_lds[192];
    __shared__ float hid[192];
    int blk = blockIdx.x;
    int b = blk / EC, e = blk % EC;
    int ai = eA[e], aj = eA[EC + e];
    int t = threadIdx.x;
    int seg = t >> 6, j = t & 63;
    float val = (seg == 0) ? x_cur[(((size_t)b << 6) + ai) * 64 + j]
              : (seg == 1) ? x_cur[(((size_t)b << 6) + aj) * 64 + j]
                           : xg[(b << 6) + j];
    in_lds[t] = val;
    __syncthreads();
    float a = 0.f;
    for (int i = 0; i < 192; i++) a += in_lds[i] * W1[i * 192 + t];
    hid[t] = fmaxf(a, 0.f);
    __syncthreads();
    if (t < 3) {
        float o = 0.f;
        for (int i = 0; i < 192; i++) o += hid[i] * W2[i * 3 + t];
        out[((size_t)b * EC + e) * 3 + t] = 1.f / (1.f + __expf(-o));
    }
}

// -------- final assembly --------
__global__ __launch_bounds__(256) void k_final(const float* __restrict__ sm, const float* __restrict__ cm,
                                               const float* __restrict__ Dinv, const float* __restrict__ Incp,
                                               const float* __restrict__ Incc, const int* __restrict__ flag,
                                               void* __restrict__ out_v) {
    int b = blockIdx.x, t = threadIdx.x;
    if (t >= 2 * MNE + VN) return;
    float val;
    if (t < MNE) {
        val = (t < EC) ? cm[((size_t)b * EC + t) * 3 + 0] - 0.5f
                       : sm[((size_t)b * NSW + (t - EC)) * 4 + 1] - 0.5f;
    } else if (t < MNE + VN) {
        int i = t - MNE;
        if (i == 0) {
            val = 1.0f;
        } else {
            float acc = 0.f;
            for (int m = 0; m < MNE; m++) {
                float ip = Incp[i * MNE + m];
                float ic = Incc[i * MNE + m];
                if (ip != 0.f || ic != 0.f) {
                    float vp, vc;
                    if (m < EC) {
                        const float* cc = cm + ((size_t)b * EC + m) * 3;
                        vp = 0.9f + 0.2f * cc[1];
                        vc = 0.9f + 0.2f * cc[2];
                    } else {
                        const float* ss = sm + ((size_t)b * NSW + (m - EC)) * 4;
                        vp = 0.9f + 0.2f * ss[2];
                        vc = 0.9f + 0.2f * ss[3];
                    }
                    acc += ip * vp + ic * vc;
                }
            }
            val = acc * Dinv[i * VN + i];
        }
    } else {
        int m = t - (MNE + VN);
        val = (m < EC) ? 1.0f : sm[((size_t)b * NSW + (m - EC)) * 4 + 0];
    }
    size_t oidx = (size_t)b * (2 * MNE + VN) + t;
    if (*flag) ((u16*)out_v)[oidx] = f2bf(val);
    else       ((float*)out_v)[oidx] = val;
}

extern "C" void kernel_launch(void* const* d_in, const int* in_sizes, int n_in,
                              void* d_out, int out_size, void* d_ws, size_t ws_size,
                              hipStream_t stream) {
    const int* eA = (const int*)d_in[21];
    const int* eS = (const int*)d_in[22];

    float* pool = (float*)d_ws;

    int off[22];
    off[0] = 0;
    for (int i = 0; i < 21; i++) off[i + 1] = off[i] + in_sizes[i];
    int cvt_total = off[21];

    const float* P_x    = pool + off[0];
    const float* P_A    = pool + off[1];
    const float* P_S    = pool + off[2];
    const float* P_emb  = pool + off[3];
    const float* P_p0Ws = pool + off[4];
    const float* P_p0Wi = pool + off[5];
    const float* P_p0Wj = pool + off[6];
    const float* P_p0U  = pool + off[7];
    const float* P_p0V  = pool + off[8];
    const float* P_plWs = pool + off[9];
    const float* P_plWi = pool + off[10];
    const float* P_plWj = pool + off[11];
    const float* P_plU  = pool + off[12];
    const float* P_plV  = pool + off[13];
    const float* P_smW1 = pool + off[14];
    const float* P_smW2 = pool + off[15];
    const float* P_cmW1 = pool + off[16];
    const float* P_cmW2 = pool + off[17];
    const float* P_Dinv = pool + off[18];
    const float* P_Incp = pool + off[19];
    const float* P_Incc = pool + off[20];

    const int NR = BN * VN * HIDD;           // 819,200
    float* tail = pool + ((cvt_total + 7) & ~7);
    float* xi    = tail;
    float* xj    = xi + NR;
    float* xv    = xj + NR;
    float* xu    = xv + NR;
    float* x_cur = xu + NR;
    float* msg   = x_cur + NR;
    float* s_edge = msg + NR;                // 200*256*64 = 3,276,800 floats
    float* xg   = s_edge + (size_t)BN * NE_MAX * 64;
    float* conn = xg + 12800;
    float* dinv = conn + 4096;
    float* ews  = dinv + 64;
    float* smo  = ews + 128;
    float* cmo  = smo + 8000;
    int*   row_ptr = (int*)(cmo + 37800);
    int*   colp    = row_ptr + 80;
    int*   sw_eidx = colp + NE_MAX;
    int*   flag    = sw_eidx + 16;

    k_detect<<<1, 64, 0, stream>>>((const u16*)d_in[1], flag);

    CvtArgs ca;
    for (int i = 0; i < 21; i++) { ca.src[i] = d_in[i]; ca.cnt[i] = in_sizes[i]; }
    k_convert<<<(cvt_total + 255) / 256, 256, 0, stream>>>(ca, pool, flag, cvt_total);

    k_setup<<<1, 256, 0, stream>>>(P_A, P_S, P_emb, P_p0Ws, eS, conn, dinv, ews,
                                   row_ptr, colp, sw_eidx);

    // layer 0
    k_xw<<<BN * VN, 256, 0, stream>>>(P_x, FINN, P_p0Wi, P_p0Wj, P_p0V, P_p0U, xi, xj, xv, xu);
    k_edge<<<BN * 16, 256, 0, stream>>>(ews, P_plWs, row_ptr, colp, dinv, xi, xj, xv,
                                        s_edge, msg, 0);
    k_node<<<BN * VN / 4, 256, 0, stream>>>(xu, msg, x_cur, 1);

    // layer 1
    k_xw<<<BN * VN, 256, 0, stream>>>(x_cur, HIDD, P_plWi, P_plWj, P_plV, P_plU, xi, xj, xv, xu);
    k_edge<<<BN * 16, 256, 0, stream>>>(ews, P_plWs, row_ptr, colp, dinv, xi, xj, xv,
                                        s_edge, msg, 1);
    k_node<<<BN * VN / 4, 256, 0, stream>>>(xu, msg, x_cur, 0);

    // layer 2
    k_xw<<<BN * VN, 256, 0, stream>>>(x_cur, HIDD, P_plWi + 4096, P_plWj + 4096,
                                      P_plV + 4096, P_plU + 4096, xi, xj, xv, xu);
    k_edge<<<BN * 16, 256, 0, stream>>>(ews, P_plWs + 4096, row_ptr, colp, dinv, xi, xj, xv,
                                        s_edge, msg, 2);
    k_node<<<BN * VN / 4, 256, 0, stream>>>(xu, msg, x_cur, 0);

    k_xg<<<BN, 64, 0, stream>>>(x_cur, xg);
    k_smlp<<<BN * NSW, 256, 0, stream>>>(s_edge, sw_eidx, eS, x_cur, xg, P_smW1, P_smW2, smo);
    k_cmlp<<<BN * EC, 192, 0, stream>>>(x_cur, xg, eA, P_cmW1, P_cmW2, cmo);
    k_final<<<BN, 256, 0, stream>>>(smo, cmo, P_Dinv, P_Incp, P_Incc, flag, d_out);
}

// Round 7
// 374.448 us; speedup vs baseline: 4.7348x; 1.1240x over previous
//
#include <hip/hip_runtime.h>

#define BN 200
#define VN 64
#define HIDD 64
#define FINN 32
#define NSW 10
#define EC 63
#define MNE 73
#define NE_MAX 256

typedef unsigned short u16;
typedef unsigned int u32;

__device__ __forceinline__ float bfu(u16 u) { return __uint_as_float(((u32)u) << 16); }
__device__ __forceinline__ u16 f2bf(float f) {
    u32 x = __float_as_uint(f);
    u32 r = x + 0x7fffu + ((x >> 16) & 1u);
    return (u16)(r >> 16);
}

// full-wave (64-lane) LayerNorm helper: relu((e-mean)*rsqrt(var+eps))
__device__ __forceinline__ float ln_relu64(float e) {
    float s1 = e, s2 = e * e;
#pragma unroll
    for (int m = 1; m < 64; m <<= 1) {
        s1 += __shfl_xor(s1, m);
        s2 += __shfl_xor(s2, m);
    }
    float mean = s1 * 0.015625f;
    float var = fmaxf(s2 * 0.015625f - mean * mean, 0.f);
    return fmaxf((e - mean) * rsqrtf(var + 1e-5f), 0.f);
}

// -------- dtype detector --------
__global__ void k_detect(const u16* __restrict__ A_u16, int* __restrict__ flag) {
    if (threadIdx.x == 0) *flag = (A_u16[1] == 0x3F80) ? 1 : 0;
}

struct CvtArgs {
    const void* src[21];
    int cnt[21];
};

__global__ __launch_bounds__(256) void k_convert(CvtArgs args, float* __restrict__ dst,
                                                 const int* __restrict__ flag, int total) {
    int fl = *flag;
    for (int idx = blockIdx.x * 256 + threadIdx.x; idx < total; idx += gridDim.x * 256) {
        int seg = 0, off = idx;
        while (off >= args.cnt[seg]) { off -= args.cnt[seg]; ++seg; }
        float v;
        if (fl) v = bfu(((const u16*)args.src[seg])[off]);
        else    v = ((const float*)args.src[seg])[off];
        dst[idx] = v;
    }
}

// -------- setup: conn, deg_inv, ews, CSR edge list (v-major), switch->edge map --------
__global__ void k_setup(const float* __restrict__ A, const float* __restrict__ S,
                        const float* __restrict__ emb, const float* __restrict__ p0Ws,
                        const int* __restrict__ eS,
                        float* __restrict__ conn, float* __restrict__ dinv,
                        float* __restrict__ ews,
                        int* __restrict__ row_ptr, int* __restrict__ colp,
                        int* __restrict__ sw_eidx) {
    __shared__ int degL[64];
    __shared__ int rpL[65];
    int t = threadIdx.x;
    for (int i = t; i < VN * VN; i += 256)
        conn[i] = fminf(A[i] + S[i], 1.0f);
    if (t < 128) {
        int j = t >> 6, k = t & 63;
        float a = 0.f;
        for (int h = 0; h < FINN; h++) a += emb[j * FINN + h] * p0Ws[h * HIDD + k];
        ews[(j << 6) + k] = a;
    }
    __syncthreads();
    if (t < 64) {
        int d = 0;
        for (int w = 0; w < 64; w++) if (conn[t * 64 + w] != 0.f) d++;
        degL[t] = d;
        dinv[t] = 1.0f / fmaxf((float)d, 1.0f);
    }
    __syncthreads();
    if (t == 0) {
        int cum = 0;
        for (int v = 0; v < 64; v++) { rpL[v] = cum; cum += degL[v]; }
        rpL[64] = cum;
        for (int v = 0; v <= 64; v++) row_ptr[v] = rpL[v];
    }
    __syncthreads();
    if (t < 64) {
        int pos = rpL[t];
        for (int w = 0; w < 64; w++)
            if (conn[t * 64 + w] != 0.f)
                colp[pos++] = w | ((S[t * 64 + w] != 0.f) ? 256 : 0);
    }
    __syncthreads();
    if (t < NSW) {
        int si = eS[t], sj = eS[NSW + t];
        int idx = 0;
        for (int e = rpL[si]; e < rpL[si + 1]; e++)
            if ((colp[e] & 255) == sj) idx = e;
        sw_eidx[t] = idx;
    }
}

// -------- node transforms, 16 rows/block: xi=x@Wi, xj=x@Wj, xv=x@Vw, xu=x@U --------
__global__ __launch_bounds__(256) void k_xw(const float* __restrict__ x, int Hin,
                                            const float* __restrict__ Wi, const float* __restrict__ Wj,
                                            const float* __restrict__ Vw, const float* __restrict__ U,
                                            float* __restrict__ xi, float* __restrict__ xj,
                                            float* __restrict__ xv, float* __restrict__ xu) {
    __shared__ float xr[16][64];
    int t = threadIdx.x;
    size_t row0 = (size_t)blockIdx.x * 16;
    if (Hin == 64) {
        for (int i = t; i < 1024; i += 256) xr[i >> 6][i & 63] = x[row0 * 64 + i];
    } else {
        for (int i = t; i < 512; i += 256) xr[i >> 5][i & 31] = x[row0 * 32 + i];
    }
    __syncthreads();
    int which = t >> 6, k = t & 63;
    const float* W = (which == 0) ? Wi : (which == 1) ? Wj : (which == 2) ? Vw : U;
    float* out = (which == 0) ? xi : (which == 1) ? xj : (which == 2) ? xv : xu;
    float acc[16];
#pragma unroll
    for (int r = 0; r < 16; r++) acc[r] = 0.f;
    for (int h = 0; h < Hin; h++) {
        float wv = W[h * 64 + k];
#pragma unroll
        for (int r = 0; r < 16; r++) acc[r] += xr[r][h] * wv;
    }
#pragma unroll
    for (int r = 0; r < 16; r++) out[(row0 + r) * 64 + k] = acc[r];
}

// -------- sparse edge kernel + fused node update --------
// wave = (b,v): chain s at CSR edges, gate+mean-agg, then x_cur update.
__global__ __launch_bounds__(256) void k_edge(
    const float* __restrict__ ews, const float* __restrict__ Ws,
    const int* __restrict__ row_ptr, const int* __restrict__ colp,
    const float* __restrict__ dinv,
    const float* __restrict__ xi, const float* __restrict__ xj,
    const float* __restrict__ xv, const float* __restrict__ xu,
    float* __restrict__ s_edge, float* __restrict__ x_cur, int layer)
{
    __shared__ float sbuf[4][64];
    int t = threadIdx.x, blk = blockIdx.x;
    int b = blk >> 4, vg = blk & 15;
    int wid = t >> 6, lane = t & 63;
    int v = (vg << 2) + wid;
    size_t rowb = (size_t)b << 6;

    float wreg[64];
    if (layer > 0) {
#pragma unroll
        for (int h = 0; h < 64; h++) wreg[h] = Ws[h * 64 + lane];
    }

    int e0 = __builtin_amdgcn_readfirstlane(row_ptr[v]);
    int e1 = __builtin_amdgcn_readfirstlane(row_ptr[v + 1]);
    float xival = xi[((rowb + v) << 6) + lane];
    float acc = 0.f;

    for (int e = e0; e < e1; e++) {
        int cp = __builtin_amdgcn_readfirstlane(colp[e]);
        int w = cp & 255;
        float xjv = xj[((rowb + w) << 6) + lane];
        float* srow = s_edge + (((size_t)b * NE_MAX + e) << 6);
        float sout;
        if (layer == 0) {
            int sidx = (cp >> 8) & 1;
            float ee = ews[(sidx << 6) + lane] + xival + xjv;
            sout = ln_relu64(ee);
        } else {
            float sp = srow[lane];
            sbuf[wid][lane] = sp;          // wave-private LDS stage (lockstep wave)
            float a = 0.f;
#pragma unroll
            for (int h = 0; h < 64; h += 4) {
                float4 s4 = *(const float4*)&sbuf[wid][h];
                a += s4.x * wreg[h] + s4.y * wreg[h + 1] + s4.z * wreg[h + 2] + s4.w * wreg[h + 3];
            }
            float ee = a + xival + xjv;
            sout = sp + ln_relu64(ee);
        }
        srow[lane] = sout;
        acc += xv[((rowb + w) << 6) + lane] / (1.f + __expf(-sout));
    }
    float mval = acc * dinv[v];

    // fused node update
    size_t idx = ((rowb + v) << 6) + lane;
    float z = xu[idx] + mval;
    float h = ln_relu64(z);
    if (layer == 0) x_cur[idx] = h;
    else            x_cur[idx] = x_cur[idx] + h;
}

// -------- x_g = sum over v --------
__global__ __launch_bounds__(256) void k_xg(const float* __restrict__ x_cur, float* __restrict__ xg) {
    __shared__ float part[4][64];
    int b = blockIdx.x, t = threadIdx.x;
    int lane = t & 63, wid = t >> 6;
    float a = 0.f;
    for (int vv = wid * 16; vv < wid * 16 + 16; vv++)
        a += x_cur[((size_t)b * VN + vv) * HIDD + lane];
    part[wid][lane] = a;
    __syncthreads();
    if (t < 64)
        xg[b * HIDD + t] = part[0][t] + part[1][t] + part[2][t] + part[3][t];
}

// -------- switch head: all 10 edges of one batch per block, tiled MLP 256->256->4 --------
__global__ __launch_bounds__(256) void k_smlp(const float* __restrict__ s_edge,
                                              const int* __restrict__ sw_eidx,
                                              const int* __restrict__ eS,
                                              const float* __restrict__ x3, const float* __restrict__ xg,
                                              const float* __restrict__ W1, const float* __restrict__ W2,
                                              float* __restrict__ out) {
    __shared__ float inb[NSW][260];
    __shared__ float hid[NSW][260];
    int b = blockIdx.x, t = threadIdx.x;
    for (int r = 0; r < NSW; r++) {
        int si = eS[r], sj = eS[NSW + r];
        float val;
        if (t < 64)       val = s_edge[(((size_t)b * NE_MAX + sw_eidx[r]) << 6) + t];
        else if (t < 128) val = x3[(((size_t)b << 6) + si) * 64 + (t - 64)];
        else if (t < 192) val = x3[(((size_t)b << 6) + sj) * 64 + (t - 128)];
        else              val = xg[(b << 6) + (t - 192)];
        inb[r][t] = val;
    }
    __syncthreads();
    float acc[NSW];
#pragma unroll
    for (int r = 0; r < NSW; r++) acc[r] = 0.f;
    for (int i = 0; i < 256; i += 4) {
        float w0 = W1[(i + 0) * 256 + t];
        float w1 = W1[(i + 1) * 256 + t];
        float w2 = W1[(i + 2) * 256 + t];
        float w3 = W1[(i + 3) * 256 + t];
#pragma unroll
        for (int r = 0; r < NSW; r++) {
            float4 v4 = *(const float4*)&inb[r][i];
            acc[r] += v4.x * w0 + v4.y * w1 + v4.z * w2 + v4.w * w3;
        }
    }
#pragma unroll
    for (int r = 0; r < NSW; r++) hid[r][t] = fmaxf(acc[r], 0.f);
    __syncthreads();
    if (t < NSW * 4) {
        int r = t >> 2, o = t & 3;
        float s = 0.f;
        for (int i = 0; i < 256; i++) s += hid[r][i] * W2[i * 4 + o];
        out[((size_t)b * NSW + r) * 4 + o] = 1.f / (1.f + __expf(-s));
    }
}

// -------- connection head: 32 edges/block, tiled MLP 192->192->3 --------
__global__ __launch_bounds__(192) void k_cmlp(const float* __restrict__ x3, const float* __restrict__ xg,
                                              const int* __restrict__ eA,
                                              const float* __restrict__ W1, const float* __restrict__ W2,
                                              float* __restrict__ out) {
    __shared__ float inb[32][196];
    __shared__ float hid[32][196];
    int blk = blockIdx.x, t = threadIdx.x;
    int b = blk >> 1, half = blk & 1;
    int ebase = half * 32;
    int nr = half ? (EC - 32) : 32;
    for (int r = 0; r < nr; r++) {
        int e = ebase + r;
        int ai = eA[e], aj = eA[EC + e];
        float val;
        if (t < 64)       val = x3[(((size_t)b << 6) + ai) * 64 + t];
        else if (t < 128) val = x3[(((size_t)b << 6) + aj) * 64 + (t - 64)];
        else              val = xg[(b << 6) + (t - 128)];
        inb[r][t] = val;
    }
    __syncthreads();
    float acc[32];
#pragma unroll
    for (int r = 0; r < 32; r++) acc[r] = 0.f;
    for (int i = 0; i < 192; i += 4) {
        float w0 = W1[(i + 0) * 192 + t];
        float w1 = W1[(i + 1) * 192 + t];
        float w2 = W1[(i + 2) * 192 + t];
        float w3 = W1[(i + 3) * 192 + t];
#pragma unroll
        for (int r = 0; r < 32; r++) {
            float4 v4 = *(const float4*)&inb[r][i];
            acc[r] += v4.x * w0 + v4.y * w1 + v4.z * w2 + v4.w * w3;
        }
    }
#pragma unroll
    for (int r = 0; r < 32; r++) hid[r][t] = fmaxf(acc[r], 0.f);
    __syncthreads();
    if (t < 96) {
        int r = t / 3, o = t - 3 * r;
        if (r < nr) {
            float s = 0.f;
            for (int i = 0; i < 192; i++) s += hid[r][i] * W2[i * 3 + o];
            out[((size_t)b * EC + ebase + r) * 3 + o] = 1.f / (1.f + __expf(-s));
        }
    }
}

// -------- final assembly --------
__global__ __launch_bounds__(256) void k_final(const float* __restrict__ sm, const float* __restrict__ cm,
                                               const float* __restrict__ Dinv, const float* __restrict__ Incp,
                                               const float* __restrict__ Incc, const int* __restrict__ flag,
                                               void* __restrict__ out_v) {
    int b = blockIdx.x, t = threadIdx.x;
    if (t >= 2 * MNE + VN) return;
    float val;
    if (t < MNE) {
        val = (t < EC) ? cm[((size_t)b * EC + t) * 3 + 0] - 0.5f
                       : sm[((size_t)b * NSW + (t - EC)) * 4 + 1] - 0.5f;
    } else if (t < MNE + VN) {
        int i = t - MNE;
        if (i == 0) {
            val = 1.0f;
        } else {
            float acc = 0.f;
            for (int m = 0; m < MNE; m++) {
                float ip = Incp[i * MNE + m];
                float ic = Incc[i * MNE + m];
                if (ip != 0.f || ic != 0.f) {
                    float vp, vc;
                    if (m < EC) {
                        const float* cc = cm + ((size_t)b * EC + m) * 3;
                        vp = 0.9f + 0.2f * cc[1];
                        vc = 0.9f + 0.2f * cc[2];
                    } else {
                        const float* ss = sm + ((size_t)b * NSW + (m - EC)) * 4;
                        vp = 0.9f + 0.2f * ss[2];
                        vc = 0.9f + 0.2f * ss[3];
                    }
                    acc += ip * vp + ic * vc;
                }
            }
            val = acc * Dinv[i * VN + i];
        }
    } else {
        int m = t - (MNE + VN);
        val = (m < EC) ? 1.0f : sm[((size_t)b * NSW + (m - EC)) * 4 + 0];
    }
    size_t oidx = (size_t)b * (2 * MNE + VN) + t;
    if (*flag) ((u16*)out_v)[oidx] = f2bf(val);
    else       ((float*)out_v)[oidx] = val;
}

extern "C" void kernel_launch(void* const* d_in, const int* in_sizes, int n_in,
                              void* d_out, int out_size, void* d_ws, size_t ws_size,
                              hipStream_t stream) {
    const int* eA = (const int*)d_in[21];
    const int* eS = (const int*)d_in[22];

    float* pool = (float*)d_ws;

    int off[22];
    off[0] = 0;
    for (int i = 0; i < 21; i++) off[i + 1] = off[i] + in_sizes[i];
    int cvt_total = off[21];

    const float* P_x    = pool + off[0];
    const float* P_A    = pool + off[1];
    const float* P_S    = pool + off[2];
    const float* P_emb  = pool + off[3];
    const float* P_p0Ws = pool + off[4];
    const float* P_p0Wi = pool + off[5];
    const float* P_p0Wj = pool + off[6];
    const float* P_p0U  = pool + off[7];
    const float* P_p0V  = pool + off[8];
    const float* P_plWs = pool + off[9];
    const float* P_plWi = pool + off[10];
    const float* P_plWj = pool + off[11];
    const float* P_plU  = pool + off[12];
    const float* P_plV  = pool + off[13];
    const float* P_smW1 = pool + off[14];
    const float* P_smW2 = pool + off[15];
    const float* P_cmW1 = pool + off[16];
    const float* P_cmW2 = pool + off[17];
    const float* P_Dinv = pool + off[18];
    const float* P_Incp = pool + off[19];
    const float* P_Incc = pool + off[20];

    const int NR = BN * VN * HIDD;           // 819,200
    float* tail = pool + ((cvt_total + 7) & ~7);
    float* xi    = tail;
    float* xj    = xi + NR;
    float* xv    = xj + NR;
    float* xu    = xv + NR;
    float* x_cur = xu + NR;
    float* s_edge = x_cur + NR;              // 200*256*64 floats
    float* xg   = s_edge + (size_t)BN * NE_MAX * 64;
    float* conn = xg + 12800;
    float* dinv = conn + 4096;
    float* ews  = dinv + 64;
    float* smo  = ews + 128;
    float* cmo  = smo + 8000;
    int*   row_ptr = (int*)(cmo + 37800);
    int*   colp    = row_ptr + 80;
    int*   sw_eidx = colp + NE_MAX;
    int*   flag    = sw_eidx + 16;

    k_detect<<<1, 64, 0, stream>>>((const u16*)d_in[1], flag);

    CvtArgs ca;
    for (int i = 0; i < 21; i++) { ca.src[i] = d_in[i]; ca.cnt[i] = in_sizes[i]; }
    k_convert<<<(cvt_total + 255) / 256, 256, 0, stream>>>(ca, pool, flag, cvt_total);

    k_setup<<<1, 256, 0, stream>>>(P_A, P_S, P_emb, P_p0Ws, eS, conn, dinv, ews,
                                   row_ptr, colp, sw_eidx);

    // layer 0
    k_xw<<<BN * VN / 16, 256, 0, stream>>>(P_x, FINN, P_p0Wi, P_p0Wj, P_p0V, P_p0U, xi, xj, xv, xu);
    k_edge<<<BN * 16, 256, 0, stream>>>(ews, P_plWs, row_ptr, colp, dinv, xi, xj, xv, xu,
                                        s_edge, x_cur, 0);
    // layer 1
    k_xw<<<BN * VN / 16, 256, 0, stream>>>(x_cur, HIDD, P_plWi, P_plWj, P_plV, P_plU, xi, xj, xv, xu);
    k_edge<<<BN * 16, 256, 0, stream>>>(ews, P_plWs, row_ptr, colp, dinv, xi, xj, xv, xu,
                                        s_edge, x_cur, 1);
    // layer 2
    k_xw<<<BN * VN / 16, 256, 0, stream>>>(x_cur, HIDD, P_plWi + 4096, P_plWj + 4096,
                                           P_plV + 4096, P_plU + 4096, xi, xj, xv, xu);
    k_edge<<<BN * 16, 256, 0, stream>>>(ews, P_plWs + 4096, row_ptr, colp, dinv, xi, xj, xv, xu,
                                        s_edge, x_cur, 2);

    k_xg<<<BN, 256, 0, stream>>>(x_cur, xg);
    k_smlp<<<BN, 256, 0, stream>>>(s_edge, sw_eidx, eS, x_cur, xg, P_smW1, P_smW2, smo);
    k_cmlp<<<BN * 2, 192, 0, stream>>>(x_cur, xg, eA, P_cmW1, P_cmW2, cmo);
    k_final<<<BN, 256, 0, stream>>>(smo, cmo, P_Dinv, P_Incp, P_Incc, flag, d_out);
}

// Round 8
// 363.679 us; speedup vs baseline: 4.8750x; 1.0296x over previous
//
#include <hip/hip_runtime.h>

#define BN 200
#define VN 64
#define HIDD 64
#define FINN 32
#define NSW 10
#define EC 63
#define MNE 73
#define NE_MAX 256

typedef unsigned short u16;
typedef unsigned int u32;

__device__ __forceinline__ float bfu(u16 u) { return __uint_as_float(((u32)u) << 16); }
__device__ __forceinline__ u16 f2bf(float f) {
    u32 x = __float_as_uint(f);
    u32 r = x + 0x7fffu + ((x >> 16) & 1u);
    return (u16)(r >> 16);
}

// broadcast lane h of v across the wave via v_readlane (VALU, not DS pipe)
__device__ __forceinline__ float rlane(float v, int h) {
    return __uint_as_float(__builtin_amdgcn_readlane(__float_as_uint(v), h));
}

// full-wave (64-lane) LayerNorm helper: relu((e-mean)*rsqrt(var+eps))
__device__ __forceinline__ float ln_relu64(float e) {
    float s1 = e, s2 = e * e;
#pragma unroll
    for (int m = 1; m < 64; m <<= 1) {
        s1 += __shfl_xor(s1, m);
        s2 += __shfl_xor(s2, m);
    }
    float mean = s1 * 0.015625f;
    float var = fmaxf(s2 * 0.015625f - mean * mean, 0.f);
    return fmaxf((e - mean) * rsqrtf(var + 1e-5f), 0.f);
}

// -------- dtype detector --------
__global__ void k_detect(const u16* __restrict__ A_u16, int* __restrict__ flag) {
    if (threadIdx.x == 0) *flag = (A_u16[1] == 0x3F80) ? 1 : 0;
}

struct CvtArgs {
    const void* src[21];
    int cnt[21];
};

__global__ __launch_bounds__(256) void k_convert(CvtArgs args, float* __restrict__ dst,
                                                 const int* __restrict__ flag, int total) {
    int fl = *flag;
    for (int idx = blockIdx.x * 256 + threadIdx.x; idx < total; idx += gridDim.x * 256) {
        int seg = 0, off = idx;
        while (off >= args.cnt[seg]) { off -= args.cnt[seg]; ++seg; }
        float v;
        if (fl) v = bfu(((const u16*)args.src[seg])[off]);
        else    v = ((const float*)args.src[seg])[off];
        dst[idx] = v;
    }
}

// -------- setup: conn, deg_inv, ews, CSR edge list (v-major), switch->edge map --------
__global__ void k_setup(const float* __restrict__ A, const float* __restrict__ S,
                        const float* __restrict__ emb, const float* __restrict__ p0Ws,
                        const int* __restrict__ eS,
                        float* __restrict__ conn, float* __restrict__ dinv,
                        float* __restrict__ ews,
                        int* __restrict__ row_ptr, int* __restrict__ colp,
                        int* __restrict__ sw_eidx) {
    __shared__ int degL[64];
    __shared__ int rpL[65];
    int t = threadIdx.x;
    for (int i = t; i < VN * VN; i += 256)
        conn[i] = fminf(A[i] + S[i], 1.0f);
    if (t < 128) {
        int j = t >> 6, k = t & 63;
        float a = 0.f;
        for (int h = 0; h < FINN; h++) a += emb[j * FINN + h] * p0Ws[h * HIDD + k];
        ews[(j << 6) + k] = a;
    }
    __syncthreads();
    if (t < 64) {
        int d = 0;
        for (int w = 0; w < 64; w++) if (conn[t * 64 + w] != 0.f) d++;
        degL[t] = d;
        dinv[t] = 1.0f / fmaxf((float)d, 1.0f);
    }
    __syncthreads();
    if (t == 0) {
        int cum = 0;
        for (int v = 0; v < 64; v++) { rpL[v] = cum; cum += degL[v]; }
        rpL[64] = cum;
        for (int v = 0; v <= 64; v++) row_ptr[v] = rpL[v];
    }
    __syncthreads();
    if (t < 64) {
        int pos = rpL[t];
        for (int w = 0; w < 64; w++)
            if (conn[t * 64 + w] != 0.f)
                colp[pos++] = w | ((S[t * 64 + w] != 0.f) ? 256 : 0);
    }
    __syncthreads();
    if (t < NSW) {
        int si = eS[t], sj = eS[NSW + t];
        int idx = 0;
        for (int e = rpL[si]; e < rpL[si + 1]; e++)
            if ((colp[e] & 255) == sj) idx = e;
        sw_eidx[t] = idx;
    }
}

// -------- node transforms, 16 rows/block, readlane broadcasts (no DS) --------
__global__ __launch_bounds__(256) void k_xw(const float* __restrict__ x, int Hin,
                                            const float* __restrict__ Wi, const float* __restrict__ Wj,
                                            const float* __restrict__ Vw, const float* __restrict__ U,
                                            float* __restrict__ xi, float* __restrict__ xj,
                                            float* __restrict__ xv, float* __restrict__ xu) {
    int t = threadIdx.x, lane = t & 63, wid = t >> 6;
    size_t row0 = (size_t)blockIdx.x * 16;
    const float* W = (wid == 0) ? Wi : (wid == 1) ? Wj : (wid == 2) ? Vw : U;
    float* out = (wid == 0) ? xi : (wid == 1) ? xj : (wid == 2) ? xv : xu;

    float xd[16];
#pragma unroll
    for (int r = 0; r < 16; r++)
        xd[r] = (Hin == 64) ? x[(row0 + r) * 64 + lane]
                            : (lane < 32 ? x[(row0 + r) * 32 + lane] : 0.f);
    float acc[16];
#pragma unroll
    for (int r = 0; r < 16; r++) acc[r] = 0.f;
    for (int h = 0; h < Hin; h++) {
        float wv = W[h * 64 + lane];
#pragma unroll
        for (int r = 0; r < 16; r++) acc[r] += rlane(xd[r], h) * wv;
    }
#pragma unroll
    for (int r = 0; r < 16; r++) out[(row0 + r) * 64 + lane] = acc[r];
}

// -------- sparse edge kernel + fused node update (readlane matvec) --------
__global__ __launch_bounds__(256) void k_edge(
    const float* __restrict__ ews, const float* __restrict__ Ws,
    const int* __restrict__ row_ptr, const int* __restrict__ colp,
    const float* __restrict__ dinv,
    const float* __restrict__ xi, const float* __restrict__ xj,
    const float* __restrict__ xv, const float* __restrict__ xu,
    float* __restrict__ s_edge, float* __restrict__ x_cur, int layer)
{
    int t = threadIdx.x, blk = blockIdx.x;
    int b = blk >> 4, vg = blk & 15;
    int wid = t >> 6, lane = t & 63;
    int v = (vg << 2) + wid;
    size_t rowb = (size_t)b << 6;

    float wreg[64];
    if (layer > 0) {
#pragma unroll
        for (int h = 0; h < 64; h++) wreg[h] = Ws[h * 64 + lane];
    }

    int e0 = __builtin_amdgcn_readfirstlane(row_ptr[v]);
    int e1 = __builtin_amdgcn_readfirstlane(row_ptr[v + 1]);
    float xival = xi[((rowb + v) << 6) + lane];
    float acc = 0.f;

    for (int e = e0; e < e1; e++) {
        int cp = __builtin_amdgcn_readfirstlane(colp[e]);
        int w = cp & 255;
        float xjv = xj[((rowb + w) << 6) + lane];
        float* srow = s_edge + (((size_t)b * NE_MAX + e) << 6);
        float sout;
        if (layer == 0) {
            int sidx = (cp >> 8) & 1;
            float ee = ews[(sidx << 6) + lane] + xival + xjv;
            sout = ln_relu64(ee);
        } else {
            float sp = srow[lane];
            float a = 0.f;
#pragma unroll
            for (int h = 0; h < 64; h++) a += rlane(sp, h) * wreg[h];
            float ee = a + xival + xjv;
            sout = sp + ln_relu64(ee);
        }
        srow[lane] = sout;
        acc += xv[((rowb + w) << 6) + lane] / (1.f + __expf(-sout));
    }
    float mval = acc * dinv[v];

    // fused node update
    size_t idx = ((rowb + v) << 6) + lane;
    float z = xu[idx] + mval;
    float h = ln_relu64(z);
    if (layer == 0) x_cur[idx] = h;
    else            x_cur[idx] = x_cur[idx] + h;
}

// -------- x_g = sum over v --------
__global__ __launch_bounds__(256) void k_xg(const float* __restrict__ x_cur, float* __restrict__ xg) {
    __shared__ float part[4][64];
    int b = blockIdx.x, t = threadIdx.x;
    int lane = t & 63, wid = t >> 6;
    float a = 0.f;
    for (int vv = wid * 16; vv < wid * 16 + 16; vv++)
        a += x_cur[((size_t)b * VN + vv) * HIDD + lane];
    part[wid][lane] = a;
    __syncthreads();
    if (t < 64)
        xg[b * HIDD + t] = part[0][t] + part[1][t] + part[2][t] + part[3][t];
}

// -------- switch head: 1 block/batch, 10 rows, readlane MLP 256->256->4 --------
__global__ __launch_bounds__(256) void k_smlp(const float* __restrict__ s_edge,
                                              const int* __restrict__ sw_eidx,
                                              const int* __restrict__ eS,
                                              const float* __restrict__ x3, const float* __restrict__ xg,
                                              const float* __restrict__ W1, const float* __restrict__ W2,
                                              float* __restrict__ out) {
    __shared__ float hid[NSW][260];
    int b = blockIdx.x, t = threadIdx.x, lane = t & 63;
    float xd0[NSW], xd1[NSW], xd2[NSW];
    float xgv = xg[(b << 6) + lane];
#pragma unroll
    for (int r = 0; r < NSW; r++) {
        int si = eS[r], sj = eS[NSW + r];
        xd0[r] = s_edge[(((size_t)b * NE_MAX + sw_eidx[r]) << 6) + lane];
        xd1[r] = x3[(((size_t)b << 6) + si) * 64 + lane];
        xd2[r] = x3[(((size_t)b << 6) + sj) * 64 + lane];
    }
    float acc[NSW];
#pragma unroll
    for (int r = 0; r < NSW; r++) acc[r] = 0.f;
    for (int h = 0; h < 64; h++) {
        float wv0 = W1[h * 256 + t];
        float wv1 = W1[(64 + h) * 256 + t];
        float wv2 = W1[(128 + h) * 256 + t];
        float wv3 = W1[(192 + h) * 256 + t];
        float s3 = rlane(xgv, h);
#pragma unroll
        for (int r = 0; r < NSW; r++)
            acc[r] += rlane(xd0[r], h) * wv0 + rlane(xd1[r], h) * wv1
                    + rlane(xd2[r], h) * wv2 + s3 * wv3;
    }
#pragma unroll
    for (int r = 0; r < NSW; r++) hid[r][t] = fmaxf(acc[r], 0.f);
    __syncthreads();
    if (t < NSW * 4) {
        int r = t >> 2, o = t & 3;
        float s = 0.f;
        for (int i = 0; i < 256; i++) s += hid[r][i] * W2[i * 4 + o];
        out[((size_t)b * NSW + r) * 4 + o] = 1.f / (1.f + __expf(-s));
    }
}

// -------- connection head: 16 edges/block (BN*4 grid), readlane MLP 192->192->3 --------
__global__ __launch_bounds__(192) void k_cmlp(const float* __restrict__ x3, const float* __restrict__ xg,
                                              const int* __restrict__ eA,
                                              const float* __restrict__ W1, const float* __restrict__ W2,
                                              float* __restrict__ out) {
    __shared__ float hid[16][200];
    int blk = blockIdx.x, t = threadIdx.x, lane = t & 63;
    int b = blk >> 2, q4 = blk & 3;
    int e0 = q4 << 4;
    int nr = (q4 == 3) ? 15 : 16;
    float xd0[16], xd1[16];
    float xgv = xg[(b << 6) + lane];
#pragma unroll
    for (int r = 0; r < 16; r++) {
        int e = e0 + r; if (e > 62) e = 62;
        int ai = eA[e], aj = eA[EC + e];
        xd0[r] = x3[(((size_t)b << 6) + ai) * 64 + lane];
        xd1[r] = x3[(((size_t)b << 6) + aj) * 64 + lane];
    }
    float acc[16];
#pragma unroll
    for (int r = 0; r < 16; r++) acc[r] = 0.f;
    for (int h = 0; h < 64; h++) {
        float wv0 = W1[h * 192 + t];
        float wv1 = W1[(64 + h) * 192 + t];
        float wv2 = W1[(128 + h) * 192 + t];
        float s2 = rlane(xgv, h);
#pragma unroll
        for (int r = 0; r < 16; r++)
            acc[r] += rlane(xd0[r], h) * wv0 + rlane(xd1[r], h) * wv1 + s2 * wv2;
    }
#pragma unroll
    for (int r = 0; r < 16; r++) hid[r][t] = fmaxf(acc[r], 0.f);
    __syncthreads();
    if (t < 48) {
        int r = t / 3, o = t - r * 3;
        if (r < nr) {
            float s = 0.f;
            for (int i = 0; i < 192; i++) s += hid[r][i] * W2[i * 3 + o];
            out[((size_t)b * EC + e0 + r) * 3 + o] = 1.f / (1.f + __expf(-s));
        }
    }
}

// -------- final assembly --------
__global__ __launch_bounds__(256) void k_final(const float* __restrict__ sm, const float* __restrict__ cm,
                                               const float* __restrict__ Dinv, const float* __restrict__ Incp,
                                               const float* __restrict__ Incc, const int* __restrict__ flag,
                                               void* __restrict__ out_v) {
    int b = blockIdx.x, t = threadIdx.x;
    if (t >= 2 * MNE + VN) return;
    float val;
    if (t < MNE) {
        val = (t < EC) ? cm[((size_t)b * EC + t) * 3 + 0] - 0.5f
                       : sm[((size_t)b * NSW + (t - EC)) * 4 + 1] - 0.5f;
    } else if (t < MNE + VN) {
        int i = t - MNE;
        if (i == 0) {
            val = 1.0f;
        } else {
            float acc = 0.f;
            for (int m = 0; m < MNE; m++) {
                float ip = Incp[i * MNE + m];
                float ic = Incc[i * MNE + m];
                if (ip != 0.f || ic != 0.f) {
                    float vp, vc;
                    if (m < EC) {
                        const float* cc = cm + ((size_t)b * EC + m) * 3;
                        vp = 0.9f + 0.2f * cc[1];
                        vc = 0.9f + 0.2f * cc[2];
                    } else {
                        const float* ss = sm + ((size_t)b * NSW + (m - EC)) * 4;
                        vp = 0.9f + 0.2f * ss[2];
                        vc = 0.9f + 0.2f * ss[3];
                    }
                    acc += ip * vp + ic * vc;
                }
            }
            val = acc * Dinv[i * VN + i];
        }
    } else {
        int m = t - (MNE + VN);
        val = (m < EC) ? 1.0f : sm[((size_t)b * NSW + (m - EC)) * 4 + 0];
    }
    size_t oidx = (size_t)b * (2 * MNE + VN) + t;
    if (*flag) ((u16*)out_v)[oidx] = f2bf(val);
    else       ((float*)out_v)[oidx] = val;
}

extern "C" void kernel_launch(void* const* d_in, const int* in_sizes, int n_in,
                              void* d_out, int out_size, void* d_ws, size_t ws_size,
                              hipStream_t stream) {
    const int* eA = (const int*)d_in[21];
    const int* eS = (const int*)d_in[22];

    float* pool = (float*)d_ws;

    int off[22];
    off[0] = 0;
    for (int i = 0; i < 21; i++) off[i + 1] = off[i] + in_sizes[i];
    int cvt_total = off[21];

    const float* P_x    = pool + off[0];
    const float* P_A    = pool + off[1];
    const float* P_S    = pool + off[2];
    const float* P_emb  = pool + off[3];
    const float* P_p0Ws = pool + off[4];
    const float* P_p0Wi = pool + off[5];
    const float* P_p0Wj = pool + off[6];
    const float* P_p0U  = pool + off[7];
    const float* P_p0V  = pool + off[8];
    const float* P_plWs = pool + off[9];
    const float* P_plWi = pool + off[10];
    const float* P_plWj = pool + off[11];
    const float* P_plU  = pool + off[12];
    const float* P_plV  = pool + off[13];
    const float* P_smW1 = pool + off[14];
    const float* P_smW2 = pool + off[15];
    const float* P_cmW1 = pool + off[16];
    const float* P_cmW2 = pool + off[17];
    const float* P_Dinv = pool + off[18];
    const float* P_Incp = pool + off[19];
    const float* P_Incc = pool + off[20];

    const int NR = BN * VN * HIDD;           // 819,200
    float* tail = pool + ((cvt_total + 7) & ~7);
    float* xi    = tail;
    float* xj    = xi + NR;
    float* xv    = xj + NR;
    float* xu    = xv + NR;
    float* x_cur = xu + NR;
    float* s_edge = x_cur + NR;              // 200*256*64 floats
    float* xg   = s_edge + (size_t)BN * NE_MAX * 64;
    float* conn = xg + 12800;
    float* dinv = conn + 4096;
    float* ews  = dinv + 64;
    float* smo  = ews + 128;
    float* cmo  = smo + 8000;
    int*   row_ptr = (int*)(cmo + 37800);
    int*   colp    = row_ptr + 80;
    int*   sw_eidx = colp + NE_MAX;
    int*   flag    = sw_eidx + 16;

    k_detect<<<1, 64, 0, stream>>>((const u16*)d_in[1], flag);

    CvtArgs ca;
    for (int i = 0; i < 21; i++) { ca.src[i] = d_in[i]; ca.cnt[i] = in_sizes[i]; }
    k_convert<<<(cvt_total + 255) / 256, 256, 0, stream>>>(ca, pool, flag, cvt_total);

    k_setup<<<1, 256, 0, stream>>>(P_A, P_S, P_emb, P_p0Ws, eS, conn, dinv, ews,
                                   row_ptr, colp, sw_eidx);

    // layer 0
    k_xw<<<BN * VN / 16, 256, 0, stream>>>(P_x, FINN, P_p0Wi, P_p0Wj, P_p0V, P_p0U, xi, xj, xv, xu);
    k_edge<<<BN * 16, 256, 0, stream>>>(ews, P_plWs, row_ptr, colp, dinv, xi, xj, xv, xu,
                                        s_edge, x_cur, 0);
    // layer 1
    k_xw<<<BN * VN / 16, 256, 0, stream>>>(x_cur, HIDD, P_plWi, P_plWj, P_plV, P_plU, xi, xj, xv, xu);
    k_edge<<<BN * 16, 256, 0, stream>>>(ews, P_plWs, row_ptr, colp, dinv, xi, xj, xv, xu,
                                        s_edge, x_cur, 1);
    // layer 2
    k_xw<<<BN * VN / 16, 256, 0, stream>>>(x_cur, HIDD, P_plWi + 4096, P_plWj + 4096,
                                           P_plV + 4096, P_plU + 4096, xi, xj, xv, xu);
    k_edge<<<BN * 16, 256, 0, stream>>>(ews, P_plWs + 4096, row_ptr, colp, dinv, xi, xj, xv, xu,
                                        s_edge, x_cur, 2);

    k_xg<<<BN, 256, 0, stream>>>(x_cur, xg);
    k_smlp<<<BN, 256, 0, stream>>>(s_edge, sw_eidx, eS, x_cur, xg, P_smW1, P_smW2, smo);
    k_cmlp<<<BN * 4, 192, 0, stream>>>(x_cur, xg, eA, P_cmW1, P_cmW2, cmo);
    k_final<<<BN, 256, 0, stream>>>(smo, cmo, P_Dinv, P_Incp, P_Incc, flag, d_out);
}

// Round 10
// 329.061 us; speedup vs baseline: 5.3879x; 1.1052x over previous
//
#include <hip/hip_runtime.h>

#define BN 200
#define VN 64
#define HIDD 64
#define FINN 32
#define NSW 10
#define EC 63
#define MNE 73
#define NE_MAX 256

typedef unsigned short u16;
typedef unsigned int u32;
typedef __attribute__((ext_vector_type(8))) short bf16x8;
typedef __attribute__((ext_vector_type(4))) float f32x4;

__device__ __forceinline__ float bfu(u16 u) { return __uint_as_float(((u32)u) << 16); }
__device__ __forceinline__ u16 f2bf(float f) {
    u32 x = __float_as_uint(f);
    u32 r = x + 0x7fffu + ((x >> 16) & 1u);
    return (u16)(r >> 16);
}

__device__ __forceinline__ float rlane(float v, int h) {
    return __uint_as_float(__builtin_amdgcn_readlane(__float_as_uint(v), h));
}

__device__ __forceinline__ float ln_relu64(float e) {
    float s1 = e, s2 = e * e;
#pragma unroll
    for (int m = 1; m < 64; m <<= 1) {
        s1 += __shfl_xor(s1, m);
        s2 += __shfl_xor(s2, m);
    }
    float mean = s1 * 0.015625f;
    float var = fmaxf(s2 * 0.015625f - mean * mean, 0.f);
    return fmaxf((e - mean) * rsqrtf(var + 1e-5f), 0.f);
}

// split 8 consecutive floats into hi/lo bf16 fragments
__device__ __forceinline__ void split8(const float* __restrict__ base, bf16x8* hi, bf16x8* lo) {
    union { bf16x8 v; u16 s[8]; } uh, ul;
#pragma unroll
    for (int j = 0; j < 8; j++) {
        float f = base[j];
        u16 h = f2bf(f);
        uh.s[j] = h;
        ul.s[j] = f2bf(f - bfu(h));
    }
    *hi = uh.v;
    *lo = ul.v;
}

struct CvtArgs {
    const void* src[21];
    int cnt[21];
};

__global__ __launch_bounds__(256) void k_convert(CvtArgs args, float* __restrict__ dst, int total) {
    int fl = (((const u16*)args.src[1])[1] == 0x3F80) ? 1 : 0;
    for (int idx = blockIdx.x * 256 + threadIdx.x; idx < total; idx += gridDim.x * 256) {
        int seg = 0, off = idx;
        while (off >= args.cnt[seg]) { off -= args.cnt[seg]; ++seg; }
        float v;
        if (fl) v = bfu(((const u16*)args.src[seg])[off]);
        else    v = ((const float*)args.src[seg])[off];
        dst[idx] = v;
    }
}

// -------- pack head weights into MFMA B-frag order, hi+lo split bf16, W2 padded to N=16 --------
__global__ __launch_bounds__(256) void k_pack(const void* cmW1, const void* cmW2,
                                              const void* smW1, const void* smW2,
                                              const u16* __restrict__ A_u16,
                                              u16* __restrict__ c1h, u16* __restrict__ c1l,
                                              u16* __restrict__ c2h, u16* __restrict__ c2l,
                                              u16* __restrict__ s1h, u16* __restrict__ s1l,
                                              u16* __restrict__ s2h, u16* __restrict__ s2l) {
    int fl = (A_u16[1] == 0x3F80) ? 1 : 0;
    const int TOT = 36864 + 3072 + 65536 + 4096;
    for (int i = blockIdx.x * 256 + threadIdx.x; i < TOT; i += gridDim.x * 256) {
        int idx = i;
        const void* src;
        u16 *dh, *dl;
        int K2, N2, nt, rem;
        if (idx < 36864) {
            nt = idx / 3072; rem = idx - nt * 3072; src = cmW1; dh = c1h + idx; dl = c1l + idx; K2 = 192; N2 = 192;
        } else if (idx < 36864 + 3072) {
            idx -= 36864; nt = 0; rem = idx; src = cmW2; dh = c2h + idx; dl = c2l + idx; K2 = 192; N2 = 3;
        } else if (idx < 36864 + 3072 + 65536) {
            idx -= 36864 + 3072; nt = idx / 4096; rem = idx - nt * 4096; src = smW1; dh = s1h + idx; dl = s1l + idx; K2 = 256; N2 = 256;
        } else {
            idx -= 36864 + 3072 + 65536; nt = 0; rem = idx; src = smW2; dh = s2h + idx; dl = s2l + idx; K2 = 256; N2 = 4;
        }
        int kb = rem >> 9, r8 = rem & 511, ln = r8 >> 3, j = r8 & 7;
        int k = kb * 32 + ((ln >> 4) << 3) + j;
        int n = nt * 16 + (ln & 15);
        float val = 0.f;
        if (n < N2 && k < K2) {
            int si = k * N2 + n;
            val = fl ? bfu(((const u16*)src)[si]) : ((const float*)src)[si];
        }
        u16 h = f2bf(val);
        *dh = h;
        *dl = f2bf(val - bfu(h));
    }
}

// -------- setup: conn, deg_inv, ews, CSR edge list, switch->edge map --------
__global__ void k_setup(const float* __restrict__ A, const float* __restrict__ S,
                        const float* __restrict__ emb, const float* __restrict__ p0Ws,
                        const int* __restrict__ eS,
                        float* __restrict__ conn, float* __restrict__ dinv,
                        float* __restrict__ ews,
                        int* __restrict__ row_ptr, int* __restrict__ colp,
                        int* __restrict__ sw_eidx) {
    __shared__ int degL[64];
    __shared__ int rpL[65];
    int t = threadIdx.x;
    for (int i = t; i < VN * VN; i += 256)
        conn[i] = fminf(A[i] + S[i], 1.0f);
    if (t < 128) {
        int j = t >> 6, k = t & 63;
        float a = 0.f;
        for (int h = 0; h < FINN; h++) a += emb[j * FINN + h] * p0Ws[h * HIDD + k];
        ews[(j << 6) + k] = a;
    }
    __syncthreads();
    if (t < 64) {
        int d = 0;
        for (int w = 0; w < 64; w++) if (conn[t * 64 + w] != 0.f) d++;
        degL[t] = d;
        dinv[t] = 1.0f / fmaxf((float)d, 1.0f);
    }
    __syncthreads();
    if (t == 0) {
        int cum = 0;
        for (int v = 0; v < 64; v++) { rpL[v] = cum; cum += degL[v]; }
        rpL[64] = cum;
        for (int v = 0; v <= 64; v++) row_ptr[v] = rpL[v];
    }
    __syncthreads();
    if (t < 64) {
        int pos = rpL[t];
        for (int w = 0; w < 64; w++)
            if (conn[t * 64 + w] != 0.f)
                colp[pos++] = w | ((S[t * 64 + w] != 0.f) ? 256 : 0);
    }
    __syncthreads();
    if (t < NSW) {
        int si = eS[t], sj = eS[NSW + t];
        int idx = 0;
        for (int e = rpL[si]; e < rpL[si + 1]; e++)
            if ((colp[e] & 255) == sj) idx = e;
        sw_eidx[t] = idx;
    }
}

// -------- node transforms, 16 rows/block, readlane broadcasts --------
__global__ __launch_bounds__(256) void k_xw(const float* __restrict__ x, int Hin,
                                            const float* __restrict__ Wi, const float* __restrict__ Wj,
                                            const float* __restrict__ Vw, const float* __restrict__ U,
                                            float* __restrict__ xi, float* __restrict__ xj,
                                            float* __restrict__ xv, float* __restrict__ xu) {
    int t = threadIdx.x, lane = t & 63, wid = t >> 6;
    size_t row0 = (size_t)blockIdx.x * 16;
    const float* W = (wid == 0) ? Wi : (wid == 1) ? Wj : (wid == 2) ? Vw : U;
    float* out = (wid == 0) ? xi : (wid == 1) ? xj : (wid == 2) ? xv : xu;

    float xd[16];
#pragma unroll
    for (int r = 0; r < 16; r++)
        xd[r] = (Hin == 64) ? x[(row0 + r) * 64 + lane]
                            : (lane < 32 ? x[(row0 + r) * 32 + lane] : 0.f);
    float acc[16];
#pragma unroll
    for (int r = 0; r < 16; r++) acc[r] = 0.f;
    for (int h = 0; h < Hin; h++) {
        float wv = W[h * 64 + lane];
#pragma unroll
        for (int r = 0; r < 16; r++) acc[r] += rlane(xd[r], h) * wv;
    }
#pragma unroll
    for (int r = 0; r < 16; r++) out[(row0 + r) * 64 + lane] = acc[r];
}

// -------- sparse edge kernel + fused node update (readlane matvec) --------
__global__ __launch_bounds__(256) void k_edge(
    const float* __restrict__ ews, const float* __restrict__ Ws,
    const int* __restrict__ row_ptr, const int* __restrict__ colp,
    const float* __restrict__ dinv,
    const float* __restrict__ xi, const float* __restrict__ xj,
    const float* __restrict__ xv, const float* __restrict__ xu,
    float* __restrict__ s_edge, float* __restrict__ x_cur, int layer)
{
    int t = threadIdx.x, blk = blockIdx.x;
    int b = blk >> 4, vg = blk & 15;
    int wid = t >> 6, lane = t & 63;
    int v = (vg << 2) + wid;
    size_t rowb = (size_t)b << 6;

    float wreg[64];
    if (layer > 0) {
#pragma unroll
        for (int h = 0; h < 64; h++) wreg[h] = Ws[h * 64 + lane];
    }

    int e0 = __builtin_amdgcn_readfirstlane(row_ptr[v]);
    int e1 = __builtin_amdgcn_readfirstlane(row_ptr[v + 1]);
    float xival = xi[((rowb + v) << 6) + lane];
    float acc = 0.f;

    for (int e = e0; e < e1; e++) {
        int cp = __builtin_amdgcn_readfirstlane(colp[e]);
        int w = cp & 255;
        float xjv = xj[((rowb + w) << 6) + lane];
        float* srow = s_edge + (((size_t)b * NE_MAX + e) << 6);
        float sout;
        if (layer == 0) {
            int sidx = (cp >> 8) & 1;
            float ee = ews[(sidx << 6) + lane] + xival + xjv;
            sout = ln_relu64(ee);
        } else {
            float sp = srow[lane];
            float a = 0.f;
#pragma unroll
            for (int h = 0; h < 64; h++) a += rlane(sp, h) * wreg[h];
            float ee = a + xival + xjv;
            sout = sp + ln_relu64(ee);
        }
        srow[lane] = sout;
        acc += xv[((rowb + w) << 6) + lane] / (1.f + __expf(-sout));
    }
    float mval = acc * dinv[v];

    size_t idx = ((rowb + v) << 6) + lane;
    float z = xu[idx] + mval;
    float h = ln_relu64(z);
    if (layer == 0) x_cur[idx] = h;
    else            x_cur[idx] = x_cur[idx] + h;
}

// -------- x_g = sum over v --------
__global__ __launch_bounds__(256) void k_xg(const float* __restrict__ x_cur, float* __restrict__ xg) {
    __shared__ float part[4][64];
    int b = blockIdx.x, t = threadIdx.x;
    int lane = t & 63, wid = t >> 6;
    float a = 0.f;
    for (int vv = wid * 16; vv < wid * 16 + 16; vv++)
        a += x_cur[((size_t)b * VN + vv) * HIDD + lane];
    part[wid][lane] = a;
    __syncthreads();
    if (t < 64)
        xg[b * HIDD + t] = part[0][t] + part[1][t] + part[2][t] + part[3][t];
}

// -------- fused heads with split-precision MFMA (hi+lo bf16 = fp32-level accuracy) --------
#define CSTR 204
#define SSTR 268
__global__ __launch_bounds__(256) void k_heads(
    const float* __restrict__ s_edge, const int* __restrict__ sw_eidx,
    const int* __restrict__ eA, const int* __restrict__ eS,
    const float* __restrict__ x3, const float* __restrict__ xg,
    const u16* __restrict__ c1h, const u16* __restrict__ c1l,
    const u16* __restrict__ c2h, const u16* __restrict__ c2l,
    const u16* __restrict__ s1h, const u16* __restrict__ s1l,
    const u16* __restrict__ s2h, const u16* __restrict__ s2l,
    float* __restrict__ cmo, float* __restrict__ smo)
{
    __shared__ float hidF[64 * CSTR];     // 52.2 KB, reused by smlp phase (16 x SSTR)
    int b = blockIdx.x, t = threadIdx.x;
    int lane = t & 63, wid = t >> 6;
    int m = lane & 15, quad = lane >> 4;
    size_t rowb = (size_t)b << 6;

    // ---- cmlp GEMM1: A rows = edges (wid*16+m), K=192 = [x3[ai], x3[aj], xg] ----
    int e = wid * 16 + m; if (e > 62) e = 62;
    int ai = eA[e], aj = eA[EC + e];
    const float* seg0 = x3 + ((rowb + ai) << 6);
    const float* seg1 = x3 + ((rowb + aj) << 6);
    const float* seg2 = xg + ((size_t)b << 6);
    f32x4 accC[12];
#pragma unroll
    for (int nt = 0; nt < 12; nt++) accC[nt] = (f32x4){0.f, 0.f, 0.f, 0.f};
#pragma unroll
    for (int kb = 0; kb < 6; kb++) {
        int k = kb * 32 + quad * 8;
        const float* base = (k < 64) ? seg0 + k : (k < 128) ? seg1 + (k - 64) : seg2 + (k - 128);
        bf16x8 ah, al;
        split8(base, &ah, &al);
#pragma unroll
        for (int nt = 0; nt < 12; nt++) {
            int o = ((nt * 6 + kb) << 9) + (lane << 3);
            bf16x8 bh = *(const bf16x8*)(c1h + o);
            bf16x8 bl = *(const bf16x8*)(c1l + o);
            accC[nt] = __builtin_amdgcn_mfma_f32_16x16x32_bf16(ah, bh, accC[nt], 0, 0, 0);
            accC[nt] = __builtin_amdgcn_mfma_f32_16x16x32_bf16(al, bh, accC[nt], 0, 0, 0);
            accC[nt] = __builtin_amdgcn_mfma_f32_16x16x32_bf16(ah, bl, accC[nt], 0, 0, 0);
        }
    }
#pragma unroll
    for (int nt = 0; nt < 12; nt++)
#pragma unroll
        for (int r = 0; r < 4; r++)
            hidF[(wid * 16 + quad * 4 + r) * CSTR + nt * 16 + m] = fmaxf(accC[nt][r], 0.f);
    __syncthreads();

    // ---- cmlp GEMM2: hid(64x192) @ W2p(192x16) ----
    f32x4 accD = (f32x4){0.f, 0.f, 0.f, 0.f};
#pragma unroll
    for (int kb = 0; kb < 6; kb++) {
        bf16x8 ah, al;
        split8(&hidF[(wid * 16 + m) * CSTR + kb * 32 + quad * 8], &ah, &al);
        int o = (kb << 9) + (lane << 3);
        bf16x8 bh = *(const bf16x8*)(c2h + o);
        bf16x8 bl = *(const bf16x8*)(c2l + o);
        accD = __builtin_amdgcn_mfma_f32_16x16x32_bf16(ah, bh, accD, 0, 0, 0);
        accD = __builtin_amdgcn_mfma_f32_16x16x32_bf16(al, bh, accD, 0, 0, 0);
        accD = __builtin_amdgcn_mfma_f32_16x16x32_bf16(ah, bl, accD, 0, 0, 0);
    }
#pragma unroll
    for (int r = 0; r < 4; r++) {
        int row = wid * 16 + quad * 4 + r;
        if (row < EC && m < 3)
            cmo[((size_t)b * EC + row) * 3 + m] = 1.f / (1.f + __expf(-accD[r]));
    }
    __syncthreads();   // all reads of hidF (cmlp) done before smlp overwrites

    // ---- smlp GEMM1: A rows = switch edges (m), K=256 = [s_edge, x3[si], x3[sj], xg] ----
    int e2 = (m > 9) ? 9 : m;
    int si = eS[e2], sj = eS[NSW + e2];
    int sw = sw_eidx[e2];
    const float* t0 = s_edge + (((size_t)b * NE_MAX + sw) << 6);
    const float* t1 = x3 + ((rowb + si) << 6);
    const float* t2 = x3 + ((rowb + sj) << 6);
    const float* t3 = xg + ((size_t)b << 6);
    f32x4 accS[4];
#pragma unroll
    for (int q2 = 0; q2 < 4; q2++) accS[q2] = (f32x4){0.f, 0.f, 0.f, 0.f};
#pragma unroll
    for (int kb = 0; kb < 8; kb++) {
        int k = kb * 32 + quad * 8;
        const float* base = (k < 64) ? t0 + k : (k < 128) ? t1 + (k - 64)
                          : (k < 192) ? t2 + (k - 128) : t3 + (k - 192);
        bf16x8 ah, al;
        split8(base, &ah, &al);
#pragma unroll
        for (int q2 = 0; q2 < 4; q2++) {
            int nt = wid * 4 + q2;
            int o = ((nt * 8 + kb) << 9) + (lane << 3);
            bf16x8 bh = *(const bf16x8*)(s1h + o);
            bf16x8 bl = *(const bf16x8*)(s1l + o);
            accS[q2] = __builtin_amdgcn_mfma_f32_16x16x32_bf16(ah, bh, accS[q2], 0, 0, 0);
            accS[q2] = __builtin_amdgcn_mfma_f32_16x16x32_bf16(al, bh, accS[q2], 0, 0, 0);
            accS[q2] = __builtin_amdgcn_mfma_f32_16x16x32_bf16(ah, bl, accS[q2], 0, 0, 0);
        }
    }
#pragma unroll
    for (int q2 = 0; q2 < 4; q2++) {
        int nt = wid * 4 + q2;
#pragma unroll
        for (int r = 0; r < 4; r++)
            hidF[(quad * 4 + r) * SSTR + nt * 16 + m] = fmaxf(accS[q2][r], 0.f);
    }
    __syncthreads();

    // ---- smlp GEMM2: hid(16x256) @ W2p(256x16), wave 0 ----
    if (wid == 0) {
        f32x4 accT = (f32x4){0.f, 0.f, 0.f, 0.f};
#pragma unroll
        for (int kb = 0; kb < 8; kb++) {
            bf16x8 ah, al;
            split8(&hidF[m * SSTR + kb * 32 + quad * 8], &ah, &al);
            int o = (kb << 9) + (lane << 3);
            bf16x8 bh = *(const bf16x8*)(s2h + o);
            bf16x8 bl = *(const bf16x8*)(s2l + o);
            accT = __builtin_amdgcn_mfma_f32_16x16x32_bf16(ah, bh, accT, 0, 0, 0);
            accT = __builtin_amdgcn_mfma_f32_16x16x32_bf16(al, bh, accT, 0, 0, 0);
            accT = __builtin_amdgcn_mfma_f32_16x16x32_bf16(ah, bl, accT, 0, 0, 0);
        }
#pragma unroll
        for (int r = 0; r < 4; r++) {
            int row = quad * 4 + r;
            if (row < NSW && m < 4)
                smo[((size_t)b * NSW + row) * 4 + m] = 1.f / (1.f + __expf(-accT[r]));
        }
    }
}

// -------- final assembly --------
__global__ __launch_bounds__(256) void k_final(const float* __restrict__ sm, const float* __restrict__ cm,
                                               const float* __restrict__ Dinv, const float* __restrict__ Incp,
                                               const float* __restrict__ Incc, const u16* __restrict__ A_u16,
                                               void* __restrict__ out_v) {
    int b = blockIdx.x, t = threadIdx.x;
    if (t >= 2 * MNE + VN) return;
    float val;
    if (t < MNE) {
        val = (t < EC) ? cm[((size_t)b * EC + t) * 3 + 0] - 0.5f
                       : sm[((size_t)b * NSW + (t - EC)) * 4 + 1] - 0.5f;
    } else if (t < MNE + VN) {
        int i = t - MNE;
        if (i == 0) {
            val = 1.0f;
        } else {
            float acc = 0.f;
            for (int m = 0; m < MNE; m++) {
                float ip = Incp[i * MNE + m];
                float ic = Incc[i * MNE + m];
                if (ip != 0.f || ic != 0.f) {
                    float vp, vc;
                    if (m < EC) {
                        const float* cc = cm + ((size_t)b * EC + m) * 3;
                        vp = 0.9f + 0.2f * cc[1];
                        vc = 0.9f + 0.2f * cc[2];
                    } else {
                        const float* ss = sm + ((size_t)b * NSW + (m - EC)) * 4;
                        vp = 0.9f + 0.2f * ss[2];
                        vc = 0.9f + 0.2f * ss[3];
                    }
                    acc += ip * vp + ic * vc;
                }
            }
            val = acc * Dinv[i * VN + i];
        }
    } else {
        int m = t - (MNE + VN);
        val = (m < EC) ? 1.0f : sm[((size_t)b * NSW + (m - EC)) * 4 + 0];
    }
    size_t oidx = (size_t)b * (2 * MNE + VN) + t;
    if (A_u16[1] == 0x3F80) ((u16*)out_v)[oidx] = f2bf(val);
    else                    ((float*)out_v)[oidx] = val;
}

extern "C" void kernel_launch(void* const* d_in, const int* in_sizes, int n_in,
                              void* d_out, int out_size, void* d_ws, size_t ws_size,
                              hipStream_t stream) {
    const int* eA = (const int*)d_in[21];
    const int* eS = (const int*)d_in[22];

    float* pool = (float*)d_ws;

    int off[22];
    off[0] = 0;
    for (int i = 0; i < 21; i++) off[i + 1] = off[i] + in_sizes[i];
    int cvt_total = off[21];

    const float* P_x    = pool + off[0];
    const float* P_A    = pool + off[1];
    const float* P_S    = pool + off[2];
    const float* P_emb  = pool + off[3];
    const float* P_p0Ws = pool + off[4];
    const float* P_p0Wi = pool + off[5];
    const float* P_p0Wj = pool + off[6];
    const float* P_p0V  = pool + off[8];
    const float* P_p0U  = pool + off[7];
    const float* P_plWs = pool + off[9];
    const float* P_plWi = pool + off[10];
    const float* P_plWj = pool + off[11];
    const float* P_plU  = pool + off[12];
    const float* P_plV  = pool + off[13];
    const float* P_Dinv = pool + off[18];
    const float* P_Incp = pool + off[19];
    const float* P_Incc = pool + off[20];

    const int NR = BN * VN * HIDD;           // 819,200
    float* tail = pool + ((cvt_total + 7) & ~7);
    float* xi    = tail;
    float* xj    = xi + NR;
    float* xv    = xj + NR;
    float* xu    = xv + NR;
    float* x_cur = xu + NR;
    float* s_edge = x_cur + NR;              // 200*256*64 floats
    float* xg   = s_edge + (size_t)BN * NE_MAX * 64;
    float* conn = xg + 12800;
    float* dinv = conn + 4096;
    float* ews  = dinv + 64;
    float* smo  = ews + 128;                 // 8000
    float* cmo  = smo + 8000;                // 37800
    u16*   c1h  = (u16*)(cmo + 37800);
    u16*   c1l  = c1h + 36864;
    u16*   c2h  = c1l + 36864;
    u16*   c2l  = c2h + 3072;
    u16*   s1h  = c2l + 3072;
    u16*   s1l  = s1h + 65536;
    u16*   s2h  = s1l + 65536;
    u16*   s2l  = s2h + 4096;
    int*   row_ptr = (int*)(s2l + 4096);
    int*   colp    = row_ptr + 80;
    int*   sw_eidx = colp + NE_MAX;

    CvtArgs ca;
    for (int i = 0; i < 21; i++) { ca.src[i] = d_in[i]; ca.cnt[i] = in_sizes[i]; }
    k_convert<<<(cvt_total + 255) / 256, 256, 0, stream>>>(ca, pool, cvt_total);

    k_pack<<<64, 256, 0, stream>>>(d_in[16], d_in[17], d_in[14], d_in[15],
                                   (const u16*)d_in[1], c1h, c1l, c2h, c2l, s1h, s1l, s2h, s2l);

    k_setup<<<1, 256, 0, stream>>>(P_A, P_S, P_emb, P_p0Ws, eS, conn, dinv, ews,
                                   row_ptr, colp, sw_eidx);

    // layer 0
    k_xw<<<BN * VN / 16, 256, 0, stream>>>(P_x, FINN, P_p0Wi, P_p0Wj, P_p0V, P_p0U, xi, xj, xv, xu);
    k_edge<<<BN * 16, 256, 0, stream>>>(ews, P_plWs, row_ptr, colp, dinv, xi, xj, xv, xu,
                                        s_edge, x_cur, 0);
    // layer 1
    k_xw<<<BN * VN / 16, 256, 0, stream>>>(x_cur, HIDD, P_plWi, P_plWj, P_plV, P_plU, xi, xj, xv, xu);
    k_edge<<<BN * 16, 256, 0, stream>>>(ews, P_plWs, row_ptr, colp, dinv, xi, xj, xv, xu,
                                        s_edge, x_cur, 1);
    // layer 2
    k_xw<<<BN * VN / 16, 256, 0, stream>>>(x_cur, HIDD, P_plWi + 4096, P_plWj + 4096,
                                           P_plV + 4096, P_plU + 4096, xi, xj, xv, xu);
    k_edge<<<BN * 16, 256, 0, stream>>>(ews, P_plWs + 4096, row_ptr, colp, dinv, xi, xj, xv, xu,
                                        s_edge, x_cur, 2);

    k_xg<<<BN, 256, 0, stream>>>(x_cur, xg);
    k_heads<<<BN, 256, 0, stream>>>(s_edge, sw_eidx, eA, eS, x_cur, xg,
                                    c1h, c1l, c2h, c2l, s1h, s1l, s2h, s2l, cmo, smo);
    k_final<<<BN, 256, 0, stream>>>(smo, cmo, P_Dinv, P_Incp, P_Incc,
                                    (const u16*)d_in[1], d_out);
}